// Round 13
// baseline (2895.300 us; speedup 1.0000x reference)
//
#include <hip/hip_runtime.h>

// ---------------- constants ----------------
constexpr int C_B   = 4;
constexpr int C_T   = 1024;
constexpr int C_D   = 768;
constexpr int C_H   = 12;
constexpr int C_HS  = 64;
constexpr int C_FF  = 3072;
constexpr int C_V   = 32000;
constexpr int C_L   = 12;
constexpr int ROWS  = C_B * C_T;      // 4096
constexpr int QKVN  = 3 * C_D;        // 2304
constexpr int NCB   = C_V / 128;      // 250 col-blocks in LM head

typedef __bf16 bf16;
typedef __attribute__((ext_vector_type(8))) __bf16 bf16x8;
typedef __attribute__((ext_vector_type(4))) float  f32x4;
typedef __attribute__((ext_vector_type(4))) short  s16x4;

static __device__ __forceinline__ void gload16(const void* g, void* l) {
  __builtin_amdgcn_global_load_lds((const __attribute__((address_space(1))) void*)g,
                                   (__attribute__((address_space(3))) void*)l,
                                   16, 0, 0);
}

// ---------------- embedding ----------------
__global__ __launch_bounds__(256) void embed_kernel(const int* __restrict__ idx,
    const float* __restrict__ tok, const float* __restrict__ pos, float* __restrict__ x) {
  int gid = blockIdx.x * 256 + threadIdx.x;
  int row = gid / C_D, d = gid - row * C_D;
  int t = row & (C_T - 1);
  x[gid] = tok[(long)idx[row] * C_D + d] + pos[(long)t * C_D + d];
}

// ---------------- layernorm ----------------
__global__ __launch_bounds__(256) void ln_kernel(const float* __restrict__ x,
    const float* __restrict__ g, const float* __restrict__ bb, long goff,
    bf16* __restrict__ out) {
  int row = blockIdx.x, tid = threadIdx.x;
  const float* xr = x + (long)row * C_D;
  float v0 = xr[tid], v1 = xr[tid + 256], v2 = xr[tid + 512];
  float s = v0 + v1 + v2;
  float s2 = v0 * v0 + v1 * v1 + v2 * v2;
#pragma unroll
  for (int off = 32; off > 0; off >>= 1) {
    s  += __shfl_down(s, off);
    s2 += __shfl_down(s2, off);
  }
  __shared__ float sm[4], sq[4];
  if ((tid & 63) == 0) { sm[tid >> 6] = s; sq[tid >> 6] = s2; }
  __syncthreads();
  s  = sm[0] + sm[1] + sm[2] + sm[3];
  s2 = sq[0] + sq[1] + sq[2] + sq[3];
  float mean = s * (1.f / C_D);
  float var  = s2 * (1.f / C_D) - mean * mean;
  float rstd = rsqrtf(var + 1e-5f);
  bf16* orow = out + (long)row * C_D;
  orow[tid]       = (bf16)((v0 - mean) * rstd * g[goff + tid]       + bb[goff + tid]);
  orow[tid + 256] = (bf16)((v1 - mean) * rstd * g[goff + tid + 256] + bb[goff + tid + 256]);
  orow[tid + 512] = (bf16)((v2 - mean) * rstd * g[goff + tid + 512] + bb[goff + tid + 512]);
}

// ---------------- generic tiled transpose+convert (Wlm) ----------------
__global__ __launch_bounds__(256) void transpose_kernel(const float* __restrict__ src,
    bf16* __restrict__ dst, int K, int N, long soff0, int ntn) {
  __shared__ bf16 tile[32][33];
  const float* s = src + soff0;
  int tn = blockIdx.x % ntn, tk = blockIdx.x / ntn;
  int c = threadIdx.x & 31, r = threadIdx.x >> 5;
#pragma unroll
  for (int it = 0; it < 4; ++it)
    tile[r + 8 * it][c] = (bf16)s[(long)(tk * 32 + r + 8 * it) * N + tn * 32 + c];
  __syncthreads();
#pragma unroll
  for (int it = 0; it < 4; ++it)
    dst[(long)(tn * 32 + r + 8 * it) * K + tk * 32 + c] = tile[c][r + 8 * it];
}

// ---------------- per-layer weight transposes, one launch (in-loop) ----------------
__global__ __launch_bounds__(256) void transpose_layer_kernel(
    const float* __restrict__ Wq, const float* __restrict__ Wk,
    const float* __restrict__ Wv, const float* __restrict__ Wo,
    const float* __restrict__ W1, const float* __restrict__ W2,
    bf16* __restrict__ wqkvt, bf16* __restrict__ wot,
    bf16* __restrict__ w1t, bf16* __restrict__ w2t, int l) {
  int bid = blockIdx.x;
  const float* src; bf16* dst; int K, N, ntn, t;
  if (bid < 1728) {
    int which = bid / 576, r = bid % 576, head = r / 48;
    t = r % 48;
    const float* W = which == 0 ? Wq : which == 1 ? Wk : Wv;
    src = W + (long)l * C_H * C_D * C_HS + (long)head * C_D * C_HS;
    dst = wqkvt + (long)which * C_D * C_D + (long)head * C_HS * C_D;
    K = C_D; N = C_HS; ntn = 2;
  } else if (bid < 2304) {
    t = bid - 1728; src = Wo + (long)l * C_D * C_D; dst = wot;
    K = C_D; N = C_D; ntn = 24;
  } else if (bid < 4608) {
    t = bid - 2304; src = W1 + (long)l * C_D * C_FF; dst = w1t;
    K = C_D; N = C_FF; ntn = 96;
  } else {
    t = bid - 4608; src = W2 + (long)l * C_FF * C_D; dst = w2t;
    K = C_FF; N = C_D; ntn = 24;
  }
  __shared__ bf16 tile[32][33];
  int tn = t % ntn, tk = t / ntn;
  int c = threadIdx.x & 31, r = threadIdx.x >> 5;
#pragma unroll
  for (int it = 0; it < 4; ++it)
    tile[r + 8 * it][c] = (bf16)src[(long)(tk * 32 + r + 8 * it) * N + tn * 32 + c];
  __syncthreads();
#pragma unroll
  for (int it = 0; it < 4; ++it)
    dst[(long)(tn * 32 + r + 8 * it) * K + tk * 32 + c] = tile[c][r + 8 * it];
}

// ======== LM-head GEMM: 128x128, BK=64, 4 waves, 64 KB LDS -> 2 blocks/CU ========
// st_16x32 subtiled staging (dec map); fp32 out + bias + fused loss partials.
// 2 blocks/CU lets one block's HBM-write epilogue hide under the other's loop.
__global__ __launch_bounds__(256) void gemm_lm(const bf16* __restrict__ A,
    const bf16* __restrict__ Bt, const float* __restrict__ bias, long boff,
    float* __restrict__ outp, float* __restrict__ lossp, int N, int K) {
  __shared__ __attribute__((aligned(16))) char smem[65536];   // 2 bufs x (A 16K | B 16K)
  int tid = threadIdx.x;
  int l = tid & 63, w = tid >> 6;
  int wm = w >> 1, wn = w & 1;
  int lg = l >> 4, lr = l & 15;

  int nwg = gridDim.x;                       // 8000
  int fid = blockIdx.x;
  int swz = (fid & 7) * (nwg >> 3) + (fid >> 3);
  long row0 = (long)(swz & 31) * 128;        // 32 row-blocks
  long col0 = (long)(swz >> 5) * 128;        // 250 col-blocks
  int cbi = (int)(col0 >> 7);

  auto dec = [](int Y, int& R, int& C) {     // LDS byte -> (row,col) of 128x64 half-tile
    int s = Y >> 10, y = Y & 1023;
    int r15 = y >> 6, z = y & 63;
    int q = (z ^ ((r15 & 8) << 2)) >> 4;
    R = (s >> 1) * 16 + r15;
    C = (s & 1) * 32 + q * 8;
  };
  int Ri[4], Ci[4];
#pragma unroll
  for (int i = 0; i < 4; ++i) dec(i * 4096 + tid * 16, Ri[i], Ci[i]);
  const bf16* Ab = A  + row0 * K;
  const bf16* Bb = Bt + col0 * K;

  auto stage = [&](int d, int kt) {          // 8 gload16 per thread
    char* bb = smem + d * 32768;
    long kc = (long)kt * 64;
#pragma unroll
    for (int i = 0; i < 4; ++i) {
      int Y = i * 4096 + tid * 16;
      gload16(Ab + (long)Ri[i] * K + kc + Ci[i], bb + Y);
      gload16(Bb + (long)Ri[i] * K + kc + Ci[i], bb + 16384 + Y);
    }
  };

  f32x4 acc[4][4];
  const f32x4 fz = {0.f, 0.f, 0.f, 0.f};
#pragma unroll
  for (int mf = 0; mf < 4; ++mf)
#pragma unroll
    for (int nf = 0; nf < 4; ++nf) acc[mf][nf] = fz;

  int aoff = lr * 64 + ((lg * 16) ^ ((lr & 8) << 2));
  int nk = K >> 6;                           // 12
  stage(0, 0);
  int d = 0;
  for (int kt = 0; kt < nk; ++kt) {
    __syncthreads();
    if (kt + 1 < nk) stage(d ^ 1, kt + 1);
    const char* aB = smem + d * 32768;
    const char* bB = smem + d * 32768 + 16384;
    bf16x8 bfrag[4][2];
#pragma unroll
    for (int nf = 0; nf < 4; ++nf)
#pragma unroll
      for (int k = 0; k < 2; ++k)
        bfrag[nf][k] = *(const bf16x8*)(bB + (((wn * 4 + nf) * 2 + k) << 10) + aoff);
    __builtin_amdgcn_s_setprio(1);
#pragma unroll
    for (int mf = 0; mf < 4; ++mf) {
      bf16x8 af[2];
#pragma unroll
      for (int k = 0; k < 2; ++k)
        af[k] = *(const bf16x8*)(aB + (((wm * 4 + mf) * 2 + k) << 10) + aoff);
#pragma unroll
      for (int nf = 0; nf < 4; ++nf)
#pragma unroll
        for (int k = 0; k < 2; ++k)
          acc[mf][nf] = __builtin_amdgcn_mfma_f32_16x16x32_bf16(
              af[k], bfrag[nf][k], acc[mf][nf], 0, 0, 0);
    }
    __builtin_amdgcn_s_setprio(0);
    d ^= 1;
  }
  __syncthreads();   // staging done; reuse all 64 KB for fp32 C tile

  // ---- epilogue: single 128x128 fp32 pass ----
  float* lf = (float*)smem;
#pragma unroll
  for (int mf = 0; mf < 4; ++mf) {
    int rl = wm * 64 + mf * 16 + lg * 4;
#pragma unroll
    for (int nf = 0; nf < 4; ++nf) {
      int col = wn * 64 + nf * 16 + lr;
      float bv = bias ? bias[boff + col0 + col] : 0.f;
#pragma unroll
      for (int r = 0; r < 4; ++r)
        lf[(rl + r) * 128 + col] = acc[mf][nf][r] + bv;
    }
  }
  __syncthreads();
#pragma unroll
  for (int it = 0; it < 16; ++it) {
    int byte = it * 4096 + tid * 16;
    int rl = byte >> 9, cb = byte & 511;
    *(f32x4*)(outp + (row0 + rl) * N + col0 + (cb >> 2)) =
        *(const f32x4*)(smem + byte);
  }
  if (lossp) {   // fused loss partials: 2 threads/row scan 64 cols each
    int row = tid >> 1, chunk = tid & 1;
    float M = -1e30f, S = 0.f;
#pragma unroll
    for (int j = 0; j < 16; ++j) {
      int jj = (j + row) & 15;
      f32x4 v = *(const f32x4*)(lf + row * 128 + chunk * 64 + jj * 4);
#pragma unroll
      for (int q = 0; q < 4; ++q) {
        float xv = v[q];
        if (xv > M) { S *= __expf(M - xv); M = xv; }
        S += __expf(xv - M);
      }
    }
    float Mo = __shfl_xor(M, 1), So = __shfl_xor(S, 1);
    float Mn = fmaxf(M, Mo);
    S = S * __expf(M - Mn) + So * __expf(Mo - Mn);
    M = Mn;
    if (chunk == 0) {
      long pi = ((row0 + row) * NCB + cbi) * 2;
      lossp[pi] = M;  lossp[pi + 1] = S;
    }
  }
}

// ---------------- 128x128 GEMM: modes 0 bf16+bias / 1 relu (QKV, FF1) ----------------
template <int MODE>
__global__ __launch_bounds__(256) void gemm_bt(const bf16* __restrict__ A,
    const bf16* __restrict__ Bt, const float* __restrict__ bias, long boff,
    void* __restrict__ outp, int N, int K) {
  __shared__ __attribute__((aligned(16))) char smem[32768];
  int tid = threadIdx.x;
  int l = tid & 63;
  int w = tid >> 6, wr = w >> 1, wc = w & 1;
  int lg = l >> 4, lr = l & 15;

  int nwg = gridDim.x;
  int fid = blockIdx.x;
  int swz = (fid & 7) * (nwg >> 3) + (fid >> 3);
  long row0 = (long)(swz & 31) * 128;
  long col0 = (long)(swz >> 5) * 128;

  const bf16* ga = A  + (row0 + (tid >> 2)) * K + (tid & 3) * 8;
  const bf16* gb = Bt + (col0 + (tid >> 2)) * K + (tid & 3) * 8;

  f32x4 acc[4][4];
  const f32x4 fz = {0.f, 0.f, 0.f, 0.f};
#pragma unroll
  for (int m = 0; m < 4; ++m)
#pragma unroll
    for (int n = 0; n < 4; ++n) acc[m][n] = fz;

  int nk = K >> 5;
  {
    bf16* la = (bf16*)smem + tid * 8;
    bf16* lb = (bf16*)(smem + 8192) + tid * 8;
    gload16(ga, la);  gload16(ga + (long)64 * K, la + 2048);
    gload16(gb, lb);  gload16(gb + (long)64 * K, lb + 2048);
    ga += 32; gb += 32;
  }
  int cur = 0;
  for (int t = 0; t < nk; ++t) {
    __syncthreads();
    if (t + 1 < nk) {
      char* bufb = smem + (cur ^ 1) * 16384;
      bf16* la = (bf16*)bufb + tid * 8;
      bf16* lb = (bf16*)(bufb + 8192) + tid * 8;
      gload16(ga, la);  gload16(ga + (long)64 * K, la + 2048);
      gload16(gb, lb);  gload16(gb + (long)64 * K, lb + 2048);
      ga += 32; gb += 32;
    }
    const bf16* cA = (const bf16*)(smem + cur * 16384);
    const bf16* cB = (const bf16*)(smem + cur * 16384 + 8192);
    bf16x8 af[4], bfr[4];
#pragma unroll
    for (int m = 0; m < 4; ++m)
      af[m] = *(const bf16x8*)(cA + (wr * 64 + m * 16 + lr) * 32 + lg * 8);
#pragma unroll
    for (int n = 0; n < 4; ++n)
      bfr[n] = *(const bf16x8*)(cB + (wc * 64 + n * 16 + lr) * 32 + lg * 8);
#pragma unroll
    for (int m = 0; m < 4; ++m)
#pragma unroll
      for (int n = 0; n < 4; ++n)
        acc[m][n] = __builtin_amdgcn_mfma_f32_16x16x32_bf16(af[m], bfr[n], acc[m][n], 0, 0, 0);
    cur ^= 1;
  }
  __syncthreads();

  bf16* lc = (bf16*)smem;
#pragma unroll
  for (int n = 0; n < 4; ++n) {
    int gcl = wc * 64 + n * 16 + lr;
    float bv = bias ? bias[boff + col0 + gcl] : 0.f;
#pragma unroll
    for (int m = 0; m < 4; ++m) {
      int rb = wr * 64 + m * 16 + lg * 4;
#pragma unroll
      for (int r = 0; r < 4; ++r) {
        float v = acc[m][n][r] + bv;
        if (MODE == 1) v = fmaxf(v, 0.f);
        lc[(rb + r) * 128 + gcl] = (bf16)v;
      }
    }
  }
  __syncthreads();
#pragma unroll
  for (int it = 0; it < 8; ++it) {
    int byte = it * 4096 + tid * 16;
    int rl = byte >> 8;
    int cb = byte & 255;
    *(bf16x8*)((bf16*)outp + (row0 + rl) * N + col0 + (cb >> 1)) =
        *(const bf16x8*)(smem + byte);
  }
}

// ---------------- 128x64 GEMM, fp32 resid += (Wo, FF2) ----------------
__global__ __launch_bounds__(256) void gemm_bt64(const bf16* __restrict__ A,
    const bf16* __restrict__ Bt, const float* __restrict__ bias, long boff,
    float* __restrict__ resid, int N, int K) {
  __shared__ __attribute__((aligned(16))) char smem[32768];
  int tid = threadIdx.x;
  int l = tid & 63;
  int w = tid >> 6, wr = w >> 1, wc = w & 1;
  int lg = l >> 4, lr = l & 15;

  int nwg = gridDim.x;
  int fid = blockIdx.x;
  int swz = (fid & 7) * (nwg >> 3) + (fid >> 3);
  long row0 = (long)(swz & 31) * 128;
  long col0 = (long)(swz >> 5) * 64;

  const bf16* ga = A  + (row0 + (tid >> 2)) * K + (tid & 3) * 8;
  const bf16* gb = Bt + (col0 + (tid >> 2)) * K + (tid & 3) * 8;

  f32x4 acc[4][2];
  const f32x4 fz = {0.f, 0.f, 0.f, 0.f};
#pragma unroll
  for (int m = 0; m < 4; ++m)
#pragma unroll
    for (int n = 0; n < 2; ++n) acc[m][n] = fz;

  int nk = K >> 5;
  {
    bf16* la = (bf16*)smem + tid * 8;
    bf16* lb = (bf16*)(smem + 8192) + tid * 8;
    gload16(ga, la);  gload16(ga + (long)64 * K, la + 2048);
    gload16(gb, lb);
    ga += 32; gb += 32;
  }
  int cur = 0;
  for (int t = 0; t < nk; ++t) {
    __syncthreads();
    if (t + 1 < nk) {
      char* bufb = smem + (cur ^ 1) * 12288;
      bf16* la = (bf16*)bufb + tid * 8;
      bf16* lb = (bf16*)(bufb + 8192) + tid * 8;
      gload16(ga, la);  gload16(ga + (long)64 * K, la + 2048);
      gload16(gb, lb);
      ga += 32; gb += 32;
    }
    const bf16* cA = (const bf16*)(smem + cur * 12288);
    const bf16* cB = (const bf16*)(smem + cur * 12288 + 8192);
    bf16x8 af[4], bfr[2];
#pragma unroll
    for (int m = 0; m < 4; ++m)
      af[m] = *(const bf16x8*)(cA + (wr * 64 + m * 16 + lr) * 32 + lg * 8);
#pragma unroll
    for (int n = 0; n < 2; ++n)
      bfr[n] = *(const bf16x8*)(cB + (wc * 32 + n * 16 + lr) * 32 + lg * 8);
#pragma unroll
    for (int m = 0; m < 4; ++m)
#pragma unroll
      for (int n = 0; n < 2; ++n)
        acc[m][n] = __builtin_amdgcn_mfma_f32_16x16x32_bf16(af[m], bfr[n], acc[m][n], 0, 0, 0);
    cur ^= 1;
  }
  __syncthreads();

  float* lcf = (float*)smem;
#pragma unroll
  for (int n = 0; n < 2; ++n) {
    int col = wc * 32 + n * 16 + lr;
    float bv = bias ? bias[boff + col0 + col] : 0.f;
#pragma unroll
    for (int m = 0; m < 4; ++m) {
      int rl = wr * 64 + m * 16 + lg * 4;
#pragma unroll
      for (int r = 0; r < 4; ++r)
        lcf[(rl + r) * 64 + col] = acc[m][n][r] + bv;
    }
  }
  __syncthreads();
#pragma unroll
  for (int it = 0; it < 8; ++it) {
    int byte = it * 4096 + tid * 16;
    int rl = byte >> 8;
    int cb = byte & 255;
    long gr = row0 + rl;
    f32x4 v = *(const f32x4*)(smem + byte);
    f32x4 g = *(const f32x4*)(resid + gr * N + col0 + (cb >> 2));
    v += g;
    *(f32x4*)(resid + gr * N + col0 + (cb >> 2)) = v;
  }
}

// ---------------- flash attention: KVBLK=32 ----------------
#define TRRD(D, OFF) asm volatile("ds_read_b64_tr_b16 %0, %1 offset:" OFF \
                                  : "=v"(D) : "v"(trp))
__global__ __launch_bounds__(64) void attn_kernel(const bf16* __restrict__ qkv,
                                                  bf16* __restrict__ attout) {
  int fid = blockIdx.x;
  int swzb = (fid & 7) * 384 + (fid >> 3);
  int qt = swzb & 63;
  int bh = swzb >> 6;
  int b = bh / C_H, h = bh % C_H;
  int l = threadIdx.x;
  int lg = l >> 4, lr = l & 15;
  const bf16* base = qkv + (long)b * C_T * QKVN;

  const bf16* qp = base + (long)(qt * 16 + lr) * QKVN + h * C_HS;
  bf16x8 qf0 = *(const bf16x8*)(qp + lg * 8);
  bf16x8 qf1 = *(const bf16x8*)(qp + 32 + lg * 8);

  const f32x4 fz = {0.f, 0.f, 0.f, 0.f};
  f32x4 o[4] = {fz, fz, fz, fz};
  float m_run[4], l_run[4];
#pragma unroll
  for (int r = 0; r < 4; ++r) { m_run[r] = -1e30f; l_run[r] = 0.f; }

  __shared__ __attribute__((aligned(16))) bf16 p_lds[16][40];
  __shared__ __attribute__((aligned(16))) bf16 vt_sub[2048];

  unsigned trp = (unsigned)(unsigned long)
      ((const __attribute__((address_space(3))) char*)vt_sub + l * 8);

  int nkt = (qt * 16 + 15) / 32 + 1;
  for (int kt = 0; kt < nkt; ++kt) {
    int key0 = kt * 32;
    f32x4 sacc[2];
#pragma unroll
    for (int ss = 0; ss < 2; ++ss) {
      const bf16* kp = base + (long)(key0 + ss * 16 + lr) * QKVN + C_D + h * C_HS;
      bf16x8 kf0 = *(const bf16x8*)(kp + lg * 8);
      bf16x8 kf1 = *(const bf16x8*)(kp + 32 + lg * 8);
      f32x4 a = fz;
      a = __builtin_amdgcn_mfma_f32_16x16x32_bf16(qf0, kf0, a, 0, 0, 0);
      a = __builtin_amdgcn_mfma_f32_16x16x32_bf16(qf1, kf1, a, 0, 0, 0);
      sacc[ss] = a;
    }
#pragma unroll
    for (int r = 0; r < 4; ++r) {
      int qrow = qt * 16 + lg * 4 + r;
      bool u0 = (key0 + lr) <= qrow;
      bool u1 = (key0 + 16 + lr) <= qrow;
      float s0 = u0 ? sacc[0][r] * 0.125f : -1e30f;
      float s1 = u1 ? sacc[1][r] * 0.125f : -1e30f;
      float mr = fmaxf(s0, s1);
      mr = fmaxf(mr, __shfl_xor(mr, 1));
      mr = fmaxf(mr, __shfl_xor(mr, 2));
      mr = fmaxf(mr, __shfl_xor(mr, 4));
      mr = fmaxf(mr, __shfl_xor(mr, 8));
      float mnew = fmaxf(m_run[r], mr);
      float scale = __expf(m_run[r] - mnew);
      float p0 = u0 ? __expf(s0 - mnew) : 0.f;
      float p1 = u1 ? __expf(s1 - mnew) : 0.f;
      float rs = p0 + p1;
      rs += __shfl_xor(rs, 1);
      rs += __shfl_xor(rs, 2);
      rs += __shfl_xor(rs, 4);
      rs += __shfl_xor(rs, 8);
      l_run[r] = l_run[r] * scale + rs;
      m_run[r] = mnew;
      o[0][r] *= scale; o[1][r] *= scale; o[2][r] *= scale; o[3][r] *= scale;
      p_lds[lg * 4 + r][lr]      = (bf16)p0;
      p_lds[lg * 4 + r][16 + lr] = (bf16)p1;
    }
#pragma unroll
    for (int it = 0; it < 4; ++it) {
      int kl = it * 8 + (l >> 3);
      int d0 = (l & 7) * 8;
      bf16x8 vv = *(const bf16x8*)(base + (long)(key0 + kl) * QKVN + 2 * C_D + h * C_HS + d0);
      int ba = ((d0 >> 4) << 10) + (((kl >> 2) & 1) << 9) + ((kl >> 3) << 7)
             + ((kl & 3) << 5) + ((d0 & 15) << 1);
      *(bf16x8*)((char*)vt_sub + ba) = vv;
    }
    __syncthreads();
    s16x4 t0a, t0b, t1a, t1b, t2a, t2b, t3a, t3b;
    TRRD(t0a, "0");    TRRD(t0b, "512");
    TRRD(t1a, "1024"); TRRD(t1b, "1536");
    TRRD(t2a, "2048"); TRRD(t2b, "2560");
    TRRD(t3a, "3072"); TRRD(t3b, "3584");
    bf16x8 pf = *(const bf16x8*)(&p_lds[lr][lg * 8]);
    asm volatile("s_waitcnt lgkmcnt(0)" ::: "memory");
    __builtin_amdgcn_sched_barrier(0);
    union uu { short s[8]; bf16x8 v; };
    auto mk = [](s16x4 a, s16x4 bq) {
      uu u;
      u.s[0] = a[0]; u.s[1] = a[1]; u.s[2] = a[2]; u.s[3] = a[3];
      u.s[4] = bq[0]; u.s[5] = bq[1]; u.s[6] = bq[2]; u.s[7] = bq[3];
      return u.v;
    };
    o[0] = __builtin_amdgcn_mfma_f32_16x16x32_bf16(pf, mk(t0a, t0b), o[0], 0, 0, 0);
    o[1] = __builtin_amdgcn_mfma_f32_16x16x32_bf16(pf, mk(t1a, t1b), o[1], 0, 0, 0);
    o[2] = __builtin_amdgcn_mfma_f32_16x16x32_bf16(pf, mk(t2a, t2b), o[2], 0, 0, 0);
    o[3] = __builtin_amdgcn_mfma_f32_16x16x32_bf16(pf, mk(t3a, t3b), o[3], 0, 0, 0);
    __syncthreads();
  }
#pragma unroll
  for (int c = 0; c < 4; ++c)
#pragma unroll
    for (int r = 0; r < 4; ++r) {
      int qrow = qt * 16 + lg * 4 + r;
      attout[((long)b * C_T + qrow) * C_D + h * C_HS + c * 16 + lr] =
          (bf16)(o[c][r] / l_run[r]);
    }
}

// ---------------- loss from partials ----------------
__global__ __launch_bounds__(128) void loss_partial_kernel(const float* __restrict__ lossp,
    const float* __restrict__ logits, const int* __restrict__ targets,
    float* __restrict__ rowloss) {
  int row = blockIdx.x * 128 + threadIdx.x;
  const float* pp = lossp + (long)row * NCB * 2;
  float M = -1e30f, S = 0.f;
  for (int i = 0; i < NCB; ++i) {
    float pm = pp[i * 2], ps = pp[i * 2 + 1];
    float Mn = fmaxf(M, pm);
    S = S * __expf(M - Mn) + ps * __expf(pm - Mn);
    M = Mn;
  }
  float lt = logits[(long)row * C_V + targets[row]];
  rowloss[row] = -(lt - M - logf(S));
}

__global__ __launch_bounds__(256) void loss_final(const float* __restrict__ rowloss,
                                                  float* __restrict__ out) {
  int tid = threadIdx.x;
  float s = 0.f;
  for (int i = tid; i < ROWS; i += 256) s += rowloss[i];
#pragma unroll
  for (int off = 32; off > 0; off >>= 1) s += __shfl_down(s, off);
  __shared__ float sm[4];
  if ((tid & 63) == 0) sm[tid >> 6] = s;
  __syncthreads();
  if (tid == 0) out[0] = (sm[0] + sm[1] + sm[2] + sm[3]) * (1.f / ROWS);
}

// ---------------- launch ----------------
extern "C" void kernel_launch(void* const* d_in, const int* in_sizes, int n_in,
                              void* d_out, int out_size, void* d_ws, size_t ws_size,
                              hipStream_t stream) {
  (void)in_sizes; (void)n_in; (void)out_size; (void)ws_size;
  const int*   idx     = (const int*)  d_in[0];
  const int*   targets = (const int*)  d_in[1];
  const float* tok     = (const float*)d_in[2];
  const float* pos     = (const float*)d_in[3];
  const float* Wq      = (const float*)d_in[4];
  const float* Wk      = (const float*)d_in[5];
  const float* Wv      = (const float*)d_in[6];
  const float* Wo      = (const float*)d_in[7];
  const float* bo      = (const float*)d_in[8];
  const float* W1      = (const float*)d_in[9];
  const float* b1      = (const float*)d_in[10];
  const float* W2      = (const float*)d_in[11];
  const float* b2      = (const float*)d_in[12];
  const float* ln1g    = (const float*)d_in[13];
  const float* ln1b    = (const float*)d_in[14];
  const float* ln2g    = (const float*)d_in[15];
  const float* ln2b    = (const float*)d_in[16];
  const float* lnfg    = (const float*)d_in[17];
  const float* lnfb    = (const float*)d_in[18];
  const float* Wlm     = (const float*)d_in[19];
  const float* blm     = (const float*)d_in[20];

  char* p = (char*)d_ws;
  auto alloc = [&](size_t bytes) {
    char* r = p; p += (bytes + 255) & ~(size_t)255; return r;
  };
  float* x       = (float*)alloc((size_t)ROWS * C_D * 4);
  bf16*  h       = (bf16*) alloc((size_t)ROWS * C_D * 2);
  bf16*  qkv     = (bf16*) alloc((size_t)ROWS * QKVN * 2);   // \  reused as wlmt
  bf16*  attout  = (bf16*) alloc((size_t)ROWS * C_D * 2);    //  > after layer loop
  bf16*  ffbuf   = (bf16*) alloc((size_t)ROWS * C_FF * 2);   // /
  bf16*  wqkvt   = (bf16*) alloc((size_t)QKVN * C_D * 2);
  bf16*  wot     = (bf16*) alloc((size_t)C_D * C_D * 2);
  bf16*  w1t     = (bf16*) alloc((size_t)C_FF * C_D * 2);
  bf16*  w2t     = (bf16*) alloc((size_t)C_D * C_FF * 2);
  float* rowloss = (float*)alloc((size_t)ROWS * 4);
  float* lossp   = (float*)alloc((size_t)ROWS * NCB * 2 * 4);   // 8.2 MB
  bf16*  wlmt    = qkv;   // alias: 49.15 MB needed, qkv+attout+ffbuf = 50.33 MB

  float* logits = (float*)d_out;

  embed_kernel<<<ROWS * C_D / 256, 256, 0, stream>>>(idx, tok, pos, x);

  for (int l = 0; l < C_L; ++l) {
    transpose_layer_kernel<<<6912, 256, 0, stream>>>(
        Wq, Wk, Wv, Wo, W1, W2, wqkvt, wot, w1t, w2t, l);

    ln_kernel<<<ROWS, 256, 0, stream>>>(x, ln1g, ln1b, (long)l * C_D, h);
    gemm_bt<0><<<(QKVN / 128) * 32, 256, 0, stream>>>(
        h, wqkvt, nullptr, 0, qkv, QKVN, C_D);
    attn_kernel<<<C_B * C_H * (C_T / 16), 64, 0, stream>>>(qkv, attout);
    gemm_bt64<<<(C_D / 64) * 32, 256, 0, stream>>>(
        attout, wot, bo, (long)l * C_D, x, C_D, C_D);
    ln_kernel<<<ROWS, 256, 0, stream>>>(x, ln2g, ln2b, (long)l * C_D, h);
    gemm_bt<1><<<(C_FF / 128) * 32, 256, 0, stream>>>(
        h, w1t, b1, (long)l * C_FF, ffbuf, C_FF, C_D);
    gemm_bt64<<<(C_D / 64) * 32, 256, 0, stream>>>(
        ffbuf, w2t, b2, (long)l * C_D, x, C_D, C_FF);
  }

  transpose_kernel<<<(C_V / 32) * (C_D / 32), 256, 0, stream>>>(
      Wlm, wlmt, C_D, C_V, 0, C_V / 32);

  ln_kernel<<<ROWS, 256, 0, stream>>>(x, lnfg, lnfb, 0, h);
  gemm_lm<<<32 * (C_V / 128), 256, 0, stream>>>(
      h, wlmt, blm, 0, logits, lossp, C_V, C_D);
  loss_partial_kernel<<<ROWS / 128, 128, 0, stream>>>(lossp, logits, targets, rowloss);
  loss_final<<<1, 256, 0, stream>>>(rowloss, logits + (long)ROWS * C_V);
}

// Round 14
// 2803.799 us; speedup vs baseline: 1.0326x; 1.0326x over previous
//
#include <hip/hip_runtime.h>

// ---------------- constants ----------------
constexpr int C_B   = 4;
constexpr int C_T   = 1024;
constexpr int C_D   = 768;
constexpr int C_H   = 12;
constexpr int C_HS  = 64;
constexpr int C_FF  = 3072;
constexpr int C_V   = 32000;
constexpr int C_L   = 12;
constexpr int ROWS  = C_B * C_T;      // 4096
constexpr int QKVN  = 3 * C_D;        // 2304
constexpr int NCB   = C_V / 256;      // 125 col-blocks in LM head

typedef __bf16 bf16;
typedef __attribute__((ext_vector_type(8))) __bf16 bf16x8;
typedef __attribute__((ext_vector_type(4))) __bf16 bf16x4;
typedef __attribute__((ext_vector_type(4))) float  f32x4;
typedef __attribute__((ext_vector_type(4))) short  s16x4;

static __device__ __forceinline__ void gload16(const void* g, void* l) {
  __builtin_amdgcn_global_load_lds((const __attribute__((address_space(1))) void*)g,
                                   (__attribute__((address_space(3))) void*)l,
                                   16, 0, 0);
}

// ---------------- embedding ----------------
__global__ __launch_bounds__(256) void embed_kernel(const int* __restrict__ idx,
    const float* __restrict__ tok, const float* __restrict__ pos, float* __restrict__ x) {
  int gid = blockIdx.x * 256 + threadIdx.x;
  int row = gid / C_D, d = gid - row * C_D;
  int t = row & (C_T - 1);
  x[gid] = tok[(long)idx[row] * C_D + d] + pos[(long)t * C_D + d];
}

// ---------------- layernorm: 1 row per wave, 8 waves/block, no block sync ----------------
__global__ __launch_bounds__(512) void ln_kernel(const float* __restrict__ x,
    const float* __restrict__ g, const float* __restrict__ bb, long goff,
    bf16* __restrict__ out) {
  int wv = threadIdx.x >> 6, lane = threadIdx.x & 63;
  long row = (long)blockIdx.x * 8 + wv;          // grid 512 -> 4096 rows
  const float* xr = x + row * C_D;
  f32x4 v[3];
#pragma unroll
  for (int j = 0; j < 3; ++j)
    v[j] = *(const f32x4*)(xr + lane * 4 + j * 256);
  float s = 0.f, s2 = 0.f;
#pragma unroll
  for (int j = 0; j < 3; ++j)
#pragma unroll
    for (int q = 0; q < 4; ++q) { float t = v[j][q]; s += t; s2 += t * t; }
#pragma unroll
  for (int off = 32; off > 0; off >>= 1) {
    s  += __shfl_down(s, off);
    s2 += __shfl_down(s2, off);
  }
  s  = __shfl(s, 0);
  s2 = __shfl(s2, 0);
  float mean = s * (1.f / C_D);
  float var  = s2 * (1.f / C_D) - mean * mean;   // biased var, matches reference
  float rstd = rsqrtf(var + 1e-5f);
  bf16* orow = out + row * C_D;
#pragma unroll
  for (int j = 0; j < 3; ++j) {
    f32x4 gv = *(const f32x4*)(g  + goff + lane * 4 + j * 256);
    f32x4 bv = *(const f32x4*)(bb + goff + lane * 4 + j * 256);
    bf16x4 o;
#pragma unroll
    for (int q = 0; q < 4; ++q)
      o[q] = (bf16)((v[j][q] - mean) * rstd * gv[q] + bv[q]);
    *(bf16x4*)(orow + lane * 4 + j * 256) = o;
  }
}

// ---------------- generic tiled transpose+convert (Wlm) ----------------
__global__ __launch_bounds__(256) void transpose_kernel(const float* __restrict__ src,
    bf16* __restrict__ dst, int K, int N, long soff0, int ntn) {
  __shared__ bf16 tile[32][33];
  const float* s = src + soff0;
  int tn = blockIdx.x % ntn, tk = blockIdx.x / ntn;
  int c = threadIdx.x & 31, r = threadIdx.x >> 5;
#pragma unroll
  for (int it = 0; it < 4; ++it)
    tile[r + 8 * it][c] = (bf16)s[(long)(tk * 32 + r + 8 * it) * N + tn * 32 + c];
  __syncthreads();
#pragma unroll
  for (int it = 0; it < 4; ++it)
    dst[(long)(tn * 32 + r + 8 * it) * K + tk * 32 + c] = tile[c][r + 8 * it];
}

// ---------------- per-layer weight transposes: 8 tiles per block ----------------
__global__ __launch_bounds__(256) void transpose_layer_kernel(
    const float* __restrict__ Wq, const float* __restrict__ Wk,
    const float* __restrict__ Wv, const float* __restrict__ Wo,
    const float* __restrict__ W1, const float* __restrict__ W2,
    bf16* __restrict__ wqkvt, bf16* __restrict__ wot,
    bf16* __restrict__ w1t, bf16* __restrict__ w2t, int l) {
  __shared__ bf16 tile[32][33];
  int c = threadIdx.x & 31, r = threadIdx.x >> 5;
  for (int sub = 0; sub < 8; ++sub) {
    int bid = blockIdx.x * 8 + sub;               // 864*8 = 6912 tiles
    const float* src; bf16* dst; int K, N, ntn, t;
    if (bid < 1728) {
      int which = bid / 576, rr = bid % 576, head = rr / 48;
      t = rr % 48;
      const float* W = which == 0 ? Wq : which == 1 ? Wk : Wv;
      src = W + (long)l * C_H * C_D * C_HS + (long)head * C_D * C_HS;
      dst = wqkvt + (long)which * C_D * C_D + (long)head * C_HS * C_D;
      K = C_D; N = C_HS; ntn = 2;
    } else if (bid < 2304) {
      t = bid - 1728; src = Wo + (long)l * C_D * C_D; dst = wot;
      K = C_D; N = C_D; ntn = 24;
    } else if (bid < 4608) {
      t = bid - 2304; src = W1 + (long)l * C_D * C_FF; dst = w1t;
      K = C_D; N = C_FF; ntn = 96;
    } else {
      t = bid - 4608; src = W2 + (long)l * C_FF * C_D; dst = w2t;
      K = C_FF; N = C_D; ntn = 24;
    }
    int tn = t % ntn, tk = t / ntn;
#pragma unroll
    for (int it = 0; it < 4; ++it)
      tile[r + 8 * it][c] = (bf16)src[(long)(tk * 32 + r + 8 * it) * N + tn * 32 + c];
    __syncthreads();
#pragma unroll
    for (int it = 0; it < 4; ++it)
      dst[(long)(tn * 32 + r + 8 * it) * K + tk * 32 + c] = tile[c][r + 8 * it];
    __syncthreads();
  }
}

// ================= 256x256 BK=64 8-wave GEMM (LM head; r11 structure) =================
// Plain __syncthreads 2-phase; balanced fp32 epilogue + fused loss partials.
__global__ __launch_bounds__(512) void gemm256(const bf16* __restrict__ A,
    const bf16* __restrict__ Bt, const float* __restrict__ bias, long boff,
    float* __restrict__ outp, float* __restrict__ lossp, int N, int K) {
  __shared__ __attribute__((aligned(16))) char smem[131072];
  int tid = threadIdx.x;
  int l = tid & 63, w = tid >> 6;
  int wm = w >> 2, wn = w & 3;
  int lg = l >> 4, lr = l & 15;

  int nwg = gridDim.x;
  int fid = blockIdx.x;
  int swz = (fid & 7) * (nwg >> 3) + (fid >> 3);
  long row0 = (long)(swz & 15) * 256;
  long col0 = (long)(swz >> 4) * 256;
  int cbi = (int)(col0 >> 8);

  int Y0 = tid * 16, Y1 = 8192 + tid * 16;
  auto dec = [](int Y, int& R, int& C) {
    int s = Y >> 10, y = Y & 1023;
    int r15 = y >> 6, z = y & 63;
    int q = (z ^ ((r15 & 8) << 2)) >> 4;
    R = (s >> 1) * 16 + r15;
    C = (s & 1) * 32 + q * 8;
  };
  int R0, C0, R1, C1;
  dec(Y0, R0, C0);  dec(Y1, R1, C1);
  const bf16* Ab = A  + row0 * K;
  const bf16* Bb = Bt + col0 * K;

  auto stage = [&](int d, int kt) {
    char* bb = smem + d * 65536;
    long kc = (long)kt * 64;
    gload16(Ab + (long)R0 * K + kc + C0, bb + Y0);
    gload16(Ab + (long)R1 * K + kc + C1, bb + Y1);
    gload16(Ab + (long)(128 + R0) * K + kc + C0, bb + 16384 + Y0);
    gload16(Ab + (long)(128 + R1) * K + kc + C1, bb + 16384 + Y1);
    gload16(Bb + (long)R0 * K + kc + C0, bb + 32768 + Y0);
    gload16(Bb + (long)R1 * K + kc + C1, bb + 32768 + Y1);
    gload16(Bb + (long)(128 + R0) * K + kc + C0, bb + 49152 + Y0);
    gload16(Bb + (long)(128 + R1) * K + kc + C1, bb + 49152 + Y1);
  };

  f32x4 acc[8][4];
  const f32x4 fz = {0.f, 0.f, 0.f, 0.f};
#pragma unroll
  for (int mf = 0; mf < 8; ++mf)
#pragma unroll
    for (int nf = 0; nf < 4; ++nf) acc[mf][nf] = fz;

  int aoff = lr * 64 + ((lg * 16) ^ ((lr & 8) << 2));
  int nk = K >> 6;
  stage(0, 0);
  int d = 0;
  for (int kt = 0; kt < nk; ++kt) {
    __syncthreads();
    if (kt + 1 < nk) stage(d ^ 1, kt + 1);
    const char* bB = smem + d * 65536 + 32768 + (wn >> 1) * 16384;
    bf16x8 bfrag[4][2];
#pragma unroll
    for (int nf = 0; nf < 4; ++nf)
#pragma unroll
      for (int k = 0; k < 2; ++k)
        bfrag[nf][k] = *(const bf16x8*)(bB + ((((wn & 1) * 4 + nf) * 2 + k) << 10) + aoff);
#pragma unroll
    for (int p = 0; p < 4; ++p) {
      bf16x8 af[2][2];
#pragma unroll
      for (int mi = 0; mi < 2; ++mi)
#pragma unroll
        for (int k = 0; k < 2; ++k) {
          int f = p * 2 + mi;
          const char* aB = smem + d * 65536 + (f >> 2) * 16384;
          af[mi][k] = *(const bf16x8*)(aB + (((wm * 4 + (f & 3)) * 2 + k) << 10) + aoff);
        }
      __builtin_amdgcn_s_setprio(1);
#pragma unroll
      for (int mi = 0; mi < 2; ++mi)
#pragma unroll
        for (int nf = 0; nf < 4; ++nf)
#pragma unroll
          for (int k = 0; k < 2; ++k)
            acc[p * 2 + mi][nf] = __builtin_amdgcn_mfma_f32_16x16x32_bf16(
                af[mi][k], bfrag[nf][k], acc[p * 2 + mi][nf], 0, 0, 0);
      __builtin_amdgcn_s_setprio(0);
    }
    d ^= 1;
  }
  __syncthreads();

  // ---- epilogue: two 128-row passes, all 8 waves fill 4 frags each pass ----
#pragma unroll
  for (int h = 0; h < 2; ++h) {
    if (h) __syncthreads();
    float* lf = (float*)smem;   // [128][256] fp32 = 128 KB
#pragma unroll
    for (int fq = 0; fq < 4; ++fq) {
      int f = h * 4 + fq;
      int rl = wm * 64 + fq * 16 + lg * 4;
#pragma unroll
      for (int nf = 0; nf < 4; ++nf) {
        int col = wn * 64 + nf * 16 + lr;
        float bv = bias ? bias[boff + col0 + col] : 0.f;
#pragma unroll
        for (int r = 0; r < 4; ++r)
          lf[(rl + r) * 256 + col] = acc[f][nf][r] + bv;
      }
    }
    __syncthreads();
#pragma unroll
    for (int it = 0; it < 16; ++it) {
      int byte = it * 8192 + tid * 16;
      int rl = byte >> 10, cb = byte & 1023;
      *(f32x4*)(outp + (row0 + h * 128 + rl) * N + col0 + (cb >> 2)) =
          *(const f32x4*)(smem + byte);
    }
    if (lossp) {   // fused loss partials: 4 threads/row, 64 cols each
      const float* lfc = (const float*)smem;
      int row = tid >> 2, chunk = tid & 3;
      float M = -1e30f, S = 0.f;
#pragma unroll
      for (int j = 0; j < 16; ++j) {
        int jj = (j + row) & 15;
        f32x4 v = *(const f32x4*)(lfc + row * 256 + chunk * 64 + jj * 4);
#pragma unroll
        for (int q = 0; q < 4; ++q) {
          float xv = v[q];
          if (xv > M) { S *= __expf(M - xv); M = xv; }
          S += __expf(xv - M);
        }
      }
#pragma unroll
      for (int off = 1; off < 4; off <<= 1) {
        float Mo = __shfl_xor(M, off), So = __shfl_xor(S, off);
        float Mn = fmaxf(M, Mo);
        S = S * __expf(M - Mn) + So * __expf(Mo - Mn);
        M = Mn;
      }
      if (chunk == 0) {
        long pi = ((row0 + h * 128 + row) * NCB + cbi) * 2;
        lossp[pi] = M;  lossp[pi + 1] = S;
      }
    }
  }
}

// ---------------- 128x128 GEMM: modes 0 bf16+bias / 1 relu (QKV, FF1) ----------------
template <int MODE>
__global__ __launch_bounds__(256) void gemm_bt(const bf16* __restrict__ A,
    const bf16* __restrict__ Bt, const float* __restrict__ bias, long boff,
    void* __restrict__ outp, int N, int K) {
  __shared__ __attribute__((aligned(16))) char smem[32768];
  int tid = threadIdx.x;
  int l = tid & 63;
  int w = tid >> 6, wr = w >> 1, wc = w & 1;
  int lg = l >> 4, lr = l & 15;

  int nwg = gridDim.x;
  int fid = blockIdx.x;
  int swz = (fid & 7) * (nwg >> 3) + (fid >> 3);
  long row0 = (long)(swz & 31) * 128;
  long col0 = (long)(swz >> 5) * 128;

  const bf16* ga = A  + (row0 + (tid >> 2)) * K + (tid & 3) * 8;
  const bf16* gb = Bt + (col0 + (tid >> 2)) * K + (tid & 3) * 8;

  f32x4 acc[4][4];
  const f32x4 fz = {0.f, 0.f, 0.f, 0.f};
#pragma unroll
  for (int m = 0; m < 4; ++m)
#pragma unroll
    for (int n = 0; n < 4; ++n) acc[m][n] = fz;

  int nk = K >> 5;
  {
    bf16* la = (bf16*)smem + tid * 8;
    bf16* lb = (bf16*)(smem + 8192) + tid * 8;
    gload16(ga, la);  gload16(ga + (long)64 * K, la + 2048);
    gload16(gb, lb);  gload16(gb + (long)64 * K, lb + 2048);
    ga += 32; gb += 32;
  }
  int cur = 0;
  for (int t = 0; t < nk; ++t) {
    __syncthreads();
    if (t + 1 < nk) {
      char* bufb = smem + (cur ^ 1) * 16384;
      bf16* la = (bf16*)bufb + tid * 8;
      bf16* lb = (bf16*)(bufb + 8192) + tid * 8;
      gload16(ga, la);  gload16(ga + (long)64 * K, la + 2048);
      gload16(gb, lb);  gload16(gb + (long)64 * K, lb + 2048);
      ga += 32; gb += 32;
    }
    const bf16* cA = (const bf16*)(smem + cur * 16384);
    const bf16* cB = (const bf16*)(smem + cur * 16384 + 8192);
    bf16x8 af[4], bfr[4];
#pragma unroll
    for (int m = 0; m < 4; ++m)
      af[m] = *(const bf16x8*)(cA + (wr * 64 + m * 16 + lr) * 32 + lg * 8);
#pragma unroll
    for (int n = 0; n < 4; ++n)
      bfr[n] = *(const bf16x8*)(cB + (wc * 64 + n * 16 + lr) * 32 + lg * 8);
#pragma unroll
    for (int m = 0; m < 4; ++m)
#pragma unroll
      for (int n = 0; n < 4; ++n)
        acc[m][n] = __builtin_amdgcn_mfma_f32_16x16x32_bf16(af[m], bfr[n], acc[m][n], 0, 0, 0);
    cur ^= 1;
  }
  __syncthreads();

  bf16* lc = (bf16*)smem;
#pragma unroll
  for (int n = 0; n < 4; ++n) {
    int gcl = wc * 64 + n * 16 + lr;
    float bv = bias ? bias[boff + col0 + gcl] : 0.f;
#pragma unroll
    for (int m = 0; m < 4; ++m) {
      int rb = wr * 64 + m * 16 + lg * 4;
#pragma unroll
      for (int r = 0; r < 4; ++r) {
        float v = acc[m][n][r] + bv;
        if (MODE == 1) v = fmaxf(v, 0.f);
        lc[(rb + r) * 128 + gcl] = (bf16)v;
      }
    }
  }
  __syncthreads();
#pragma unroll
  for (int it = 0; it < 8; ++it) {
    int byte = it * 4096 + tid * 16;
    int rl = byte >> 8;
    int cb = byte & 255;
    *(bf16x8*)((bf16*)outp + (row0 + rl) * N + col0 + (cb >> 1)) =
        *(const bf16x8*)(smem + byte);
  }
}

// ---------------- 128x64 GEMM, fp32 resid += (Wo, FF2) ----------------
__global__ __launch_bounds__(256) void gemm_bt64(const bf16* __restrict__ A,
    const bf16* __restrict__ Bt, const float* __restrict__ bias, long boff,
    float* __restrict__ resid, int N, int K) {
  __shared__ __attribute__((aligned(16))) char smem[32768];
  int tid = threadIdx.x;
  int l = tid & 63;
  int w = tid >> 6, wr = w >> 1, wc = w & 1;
  int lg = l >> 4, lr = l & 15;

  int nwg = gridDim.x;
  int fid = blockIdx.x;
  int swz = (fid & 7) * (nwg >> 3) + (fid >> 3);
  long row0 = (long)(swz & 31) * 128;
  long col0 = (long)(swz >> 5) * 64;

  const bf16* ga = A  + (row0 + (tid >> 2)) * K + (tid & 3) * 8;
  const bf16* gb = Bt + (col0 + (tid >> 2)) * K + (tid & 3) * 8;

  f32x4 acc[4][2];
  const f32x4 fz = {0.f, 0.f, 0.f, 0.f};
#pragma unroll
  for (int m = 0; m < 4; ++m)
#pragma unroll
    for (int n = 0; n < 2; ++n) acc[m][n] = fz;

  int nk = K >> 5;
  {
    bf16* la = (bf16*)smem + tid * 8;
    bf16* lb = (bf16*)(smem + 8192) + tid * 8;
    gload16(ga, la);  gload16(ga + (long)64 * K, la + 2048);
    gload16(gb, lb);
    ga += 32; gb += 32;
  }
  int cur = 0;
  for (int t = 0; t < nk; ++t) {
    __syncthreads();
    if (t + 1 < nk) {
      char* bufb = smem + (cur ^ 1) * 12288;
      bf16* la = (bf16*)bufb + tid * 8;
      bf16* lb = (bf16*)(bufb + 8192) + tid * 8;
      gload16(ga, la);  gload16(ga + (long)64 * K, la + 2048);
      gload16(gb, lb);
      ga += 32; gb += 32;
    }
    const bf16* cA = (const bf16*)(smem + cur * 12288);
    const bf16* cB = (const bf16*)(smem + cur * 12288 + 8192);
    bf16x8 af[4], bfr[2];
#pragma unroll
    for (int m = 0; m < 4; ++m)
      af[m] = *(const bf16x8*)(cA + (wr * 64 + m * 16 + lr) * 32 + lg * 8);
#pragma unroll
    for (int n = 0; n < 2; ++n)
      bfr[n] = *(const bf16x8*)(cB + (wc * 32 + n * 16 + lr) * 32 + lg * 8);
#pragma unroll
    for (int m = 0; m < 4; ++m)
#pragma unroll
      for (int n = 0; n < 2; ++n)
        acc[m][n] = __builtin_amdgcn_mfma_f32_16x16x32_bf16(af[m], bfr[n], acc[m][n], 0, 0, 0);
    cur ^= 1;
  }
  __syncthreads();

  float* lcf = (float*)smem;
#pragma unroll
  for (int n = 0; n < 2; ++n) {
    int col = wc * 32 + n * 16 + lr;
    float bv = bias ? bias[boff + col0 + col] : 0.f;
#pragma unroll
    for (int m = 0; m < 4; ++m) {
      int rl = wr * 64 + m * 16 + lg * 4;
#pragma unroll
      for (int r = 0; r < 4; ++r)
        lcf[(rl + r) * 64 + col] = acc[m][n][r] + bv;
    }
  }
  __syncthreads();
#pragma unroll
  for (int it = 0; it < 8; ++it) {
    int byte = it * 4096 + tid * 16;
    int rl = byte >> 8;
    int cb = byte & 255;
    long gr = row0 + rl;
    f32x4 v = *(const f32x4*)(smem + byte);
    f32x4 g = *(const f32x4*)(resid + gr * N + col0 + (cb >> 2));
    v += g;
    *(f32x4*)(resid + gr * N + col0 + (cb >> 2)) = v;
  }
}

// ---------------- flash attention: KVBLK=32 ----------------
#define TRRD(D, OFF) asm volatile("ds_read_b64_tr_b16 %0, %1 offset:" OFF \
                                  : "=v"(D) : "v"(trp))
__global__ __launch_bounds__(64) void attn_kernel(const bf16* __restrict__ qkv,
                                                  bf16* __restrict__ attout) {
  int fid = blockIdx.x;
  int swzb = (fid & 7) * 384 + (fid >> 3);
  int qt = swzb & 63;
  int bh = swzb >> 6;
  int b = bh / C_H, h = bh % C_H;
  int l = threadIdx.x;
  int lg = l >> 4, lr = l & 15;
  const bf16* base = qkv + (long)b * C_T * QKVN;

  const bf16* qp = base + (long)(qt * 16 + lr) * QKVN + h * C_HS;
  bf16x8 qf0 = *(const bf16x8*)(qp + lg * 8);
  bf16x8 qf1 = *(const bf16x8*)(qp + 32 + lg * 8);

  const f32x4 fz = {0.f, 0.f, 0.f, 0.f};
  f32x4 o[4] = {fz, fz, fz, fz};
  float m_run[4], l_run[4];
#pragma unroll
  for (int r = 0; r < 4; ++r) { m_run[r] = -1e30f; l_run[r] = 0.f; }

  __shared__ __attribute__((aligned(16))) bf16 p_lds[16][40];
  __shared__ __attribute__((aligned(16))) bf16 vt_sub[2048];

  unsigned trp = (unsigned)(unsigned long)
      ((const __attribute__((address_space(3))) char*)vt_sub + l * 8);

  int nkt = (qt * 16 + 15) / 32 + 1;
  for (int kt = 0; kt < nkt; ++kt) {
    int key0 = kt * 32;
    f32x4 sacc[2];
#pragma unroll
    for (int ss = 0; ss < 2; ++ss) {
      const bf16* kp = base + (long)(key0 + ss * 16 + lr) * QKVN + C_D + h * C_HS;
      bf16x8 kf0 = *(const bf16x8*)(kp + lg * 8);
      bf16x8 kf1 = *(const bf16x8*)(kp + 32 + lg * 8);
      f32x4 a = fz;
      a = __builtin_amdgcn_mfma_f32_16x16x32_bf16(qf0, kf0, a, 0, 0, 0);
      a = __builtin_amdgcn_mfma_f32_16x16x32_bf16(qf1, kf1, a, 0, 0, 0);
      sacc[ss] = a;
    }
#pragma unroll
    for (int r = 0; r < 4; ++r) {
      int qrow = qt * 16 + lg * 4 + r;
      bool u0 = (key0 + lr) <= qrow;
      bool u1 = (key0 + 16 + lr) <= qrow;
      float s0 = u0 ? sacc[0][r] * 0.125f : -1e30f;
      float s1 = u1 ? sacc[1][r] * 0.125f : -1e30f;
      float mr = fmaxf(s0, s1);
      mr = fmaxf(mr, __shfl_xor(mr, 1));
      mr = fmaxf(mr, __shfl_xor(mr, 2));
      mr = fmaxf(mr, __shfl_xor(mr, 4));
      mr = fmaxf(mr, __shfl_xor(mr, 8));
      float mnew = fmaxf(m_run[r], mr);
      float scale = __expf(m_run[r] - mnew);
      float p0 = u0 ? __expf(s0 - mnew) : 0.f;
      float p1 = u1 ? __expf(s1 - mnew) : 0.f;
      float rs = p0 + p1;
      rs += __shfl_xor(rs, 1);
      rs += __shfl_xor(rs, 2);
      rs += __shfl_xor(rs, 4);
      rs += __shfl_xor(rs, 8);
      l_run[r] = l_run[r] * scale + rs;
      m_run[r] = mnew;
      o[0][r] *= scale; o[1][r] *= scale; o[2][r] *= scale; o[3][r] *= scale;
      p_lds[lg * 4 + r][lr]      = (bf16)p0;
      p_lds[lg * 4 + r][16 + lr] = (bf16)p1;
    }
#pragma unroll
    for (int it = 0; it < 4; ++it) {
      int kl = it * 8 + (l >> 3);
      int d0 = (l & 7) * 8;
      bf16x8 vv = *(const bf16x8*)(base + (long)(key0 + kl) * QKVN + 2 * C_D + h * C_HS + d0);
      int ba = ((d0 >> 4) << 10) + (((kl >> 2) & 1) << 9) + ((kl >> 3) << 7)
             + ((kl & 3) << 5) + ((d0 & 15) << 1);
      *(bf16x8*)((char*)vt_sub + ba) = vv;
    }
    __syncthreads();
    s16x4 t0a, t0b, t1a, t1b, t2a, t2b, t3a, t3b;
    TRRD(t0a, "0");    TRRD(t0b, "512");
    TRRD(t1a, "1024"); TRRD(t1b, "1536");
    TRRD(t2a, "2048"); TRRD(t2b, "2560");
    TRRD(t3a, "3072"); TRRD(t3b, "3584");
    bf16x8 pf = *(const bf16x8*)(&p_lds[lr][lg * 8]);
    asm volatile("s_waitcnt lgkmcnt(0)" ::: "memory");
    __builtin_amdgcn_sched_barrier(0);
    union uu { short s[8]; bf16x8 v; };
    auto mk = [](s16x4 a, s16x4 bq) {
      uu u;
      u.s[0] = a[0]; u.s[1] = a[1]; u.s[2] = a[2]; u.s[3] = a[3];
      u.s[4] = bq[0]; u.s[5] = bq[1]; u.s[6] = bq[2]; u.s[7] = bq[3];
      return u.v;
    };
    o[0] = __builtin_amdgcn_mfma_f32_16x16x32_bf16(pf, mk(t0a, t0b), o[0], 0, 0, 0);
    o[1] = __builtin_amdgcn_mfma_f32_16x16x32_bf16(pf, mk(t1a, t1b), o[1], 0, 0, 0);
    o[2] = __builtin_amdgcn_mfma_f32_16x16x32_bf16(pf, mk(t2a, t2b), o[2], 0, 0, 0);
    o[3] = __builtin_amdgcn_mfma_f32_16x16x32_bf16(pf, mk(t3a, t3b), o[3], 0, 0, 0);
    __syncthreads();
  }
#pragma unroll
  for (int c = 0; c < 4; ++c)
#pragma unroll
    for (int r = 0; r < 4; ++r) {
      int qrow = qt * 16 + lg * 4 + r;
      attout[((long)b * C_T + qrow) * C_D + h * C_HS + c * 16 + lr] =
          (bf16)(o[c][r] / l_run[r]);
    }
}

// ---------------- loss from partials ----------------
__global__ __launch_bounds__(128) void loss_partial_kernel(const float* __restrict__ lossp,
    const float* __restrict__ logits, const int* __restrict__ targets,
    float* __restrict__ rowloss) {
  int row = blockIdx.x * 128 + threadIdx.x;
  const float* pp = lossp + (long)row * NCB * 2;
  float M = -1e30f, S = 0.f;
  for (int i = 0; i < NCB; ++i) {
    float pm = pp[i * 2], ps = pp[i * 2 + 1];
    float Mn = fmaxf(M, pm);
    S = S * __expf(M - Mn) + ps * __expf(pm - Mn);
    M = Mn;
  }
  float lt = logits[(long)row * C_V + targets[row]];
  rowloss[row] = -(lt - M - logf(S));
}

__global__ __launch_bounds__(256) void loss_final(const float* __restrict__ rowloss,
                                                  float* __restrict__ out) {
  int tid = threadIdx.x;
  float s = 0.f;
  for (int i = tid; i < ROWS; i += 256) s += rowloss[i];
#pragma unroll
  for (int off = 32; off > 0; off >>= 1) s += __shfl_down(s, off);
  __shared__ float sm[4];
  if ((tid & 63) == 0) sm[tid >> 6] = s;
  __syncthreads();
  if (tid == 0) out[0] = (sm[0] + sm[1] + sm[2] + sm[3]) * (1.f / ROWS);
}

// ---------------- launch ----------------
extern "C" void kernel_launch(void* const* d_in, const int* in_sizes, int n_in,
                              void* d_out, int out_size, void* d_ws, size_t ws_size,
                              hipStream_t stream) {
  (void)in_sizes; (void)n_in; (void)out_size; (void)ws_size;
  const int*   idx     = (const int*)  d_in[0];
  const int*   targets = (const int*)  d_in[1];
  const float* tok     = (const float*)d_in[2];
  const float* pos     = (const float*)d_in[3];
  const float* Wq      = (const float*)d_in[4];
  const float* Wk      = (const float*)d_in[5];
  const float* Wv      = (const float*)d_in[6];
  const float* Wo      = (const float*)d_in[7];
  const float* bo      = (const float*)d_in[8];
  const float* W1      = (const float*)d_in[9];
  const float* b1      = (const float*)d_in[10];
  const float* W2      = (const float*)d_in[11];
  const float* b2      = (const float*)d_in[12];
  const float* ln1g    = (const float*)d_in[13];
  const float* ln1b    = (const float*)d_in[14];
  const float* ln2g    = (const float*)d_in[15];
  const float* ln2b    = (const float*)d_in[16];
  const float* lnfg    = (const float*)d_in[17];
  const float* lnfb    = (const float*)d_in[18];
  const float* Wlm     = (const float*)d_in[19];
  const float* blm     = (const float*)d_in[20];

  char* p = (char*)d_ws;
  auto alloc = [&](size_t bytes) {
    char* r = p; p += (bytes + 255) & ~(size_t)255; return r;
  };
  float* x       = (float*)alloc((size_t)ROWS * C_D * 4);
  bf16*  h       = (bf16*) alloc((size_t)ROWS * C_D * 2);
  bf16*  qkv     = (bf16*) alloc((size_t)ROWS * QKVN * 2);   // \  reused as wlmt
  bf16*  attout  = (bf16*) alloc((size_t)ROWS * C_D * 2);    //  > after layer loop
  bf16*  ffbuf   = (bf16*) alloc((size_t)ROWS * C_FF * 2);   // /
  bf16*  wqkvt   = (bf16*) alloc((size_t)QKVN * C_D * 2);
  bf16*  wot     = (bf16*) alloc((size_t)C_D * C_D * 2);
  bf16*  w1t     = (bf16*) alloc((size_t)C_FF * C_D * 2);
  bf16*  w2t     = (bf16*) alloc((size_t)C_D * C_FF * 2);
  float* rowloss = (float*)alloc((size_t)ROWS * 4);
  float* lossp   = (float*)alloc((size_t)ROWS * NCB * 2 * 4);
  bf16*  wlmt    = qkv;   // alias: 49.15 MB needed, qkv+attout+ffbuf = 50.33 MB

  float* logits = (float*)d_out;

  embed_kernel<<<ROWS * C_D / 256, 256, 0, stream>>>(idx, tok, pos, x);

  for (int l = 0; l < C_L; ++l) {
    transpose_layer_kernel<<<864, 256, 0, stream>>>(
        Wq, Wk, Wv, Wo, W1, W2, wqkvt, wot, w1t, w2t, l);

    ln_kernel<<<ROWS / 8, 512, 0, stream>>>(x, ln1g, ln1b, (long)l * C_D, h);
    gemm_bt<0><<<(QKVN / 128) * 32, 256, 0, stream>>>(
        h, wqkvt, nullptr, 0, qkv, QKVN, C_D);
    attn_kernel<<<C_B * C_H * (C_T / 16), 64, 0, stream>>>(qkv, attout);
    gemm_bt64<<<(C_D / 64) * 32, 256, 0, stream>>>(
        attout, wot, bo, (long)l * C_D, x, C_D, C_D);
    ln_kernel<<<ROWS / 8, 512, 0, stream>>>(x, ln2g, ln2b, (long)l * C_D, h);
    gemm_bt<1><<<(C_FF / 128) * 32, 256, 0, stream>>>(
        h, w1t, b1, (long)l * C_FF, ffbuf, C_FF, C_D);
    gemm_bt64<<<(C_D / 64) * 32, 256, 0, stream>>>(
        ffbuf, w2t, b2, (long)l * C_D, x, C_D, C_FF);
  }

  transpose_kernel<<<(C_V / 32) * (C_D / 32), 256, 0, stream>>>(
      Wlm, wlmt, C_D, C_V, 0, C_V / 32);

  ln_kernel<<<ROWS / 8, 512, 0, stream>>>(x, lnfg, lnfb, 0, h);
  gemm256<<<16 * (C_V / 256), 512, 0, stream>>>(
      h, wlmt, blm, 0, logits, lossp, C_V, C_D);
  loss_partial_kernel<<<ROWS / 128, 128, 0, stream>>>(lossp, logits, targets, rowloss);
  loss_final<<<1, 256, 0, stream>>>(rowloss, logits + (long)ROWS * C_V);
}

// Round 15
// 2800.531 us; speedup vs baseline: 1.0338x; 1.0012x over previous
//
#include <hip/hip_runtime.h>

// ---------------- constants ----------------
constexpr int C_B   = 4;
constexpr int C_T   = 1024;
constexpr int C_D   = 768;
constexpr int C_H   = 12;
constexpr int C_HS  = 64;
constexpr int C_FF  = 3072;
constexpr int C_V   = 32000;
constexpr int C_L   = 12;
constexpr int ROWS  = C_B * C_T;      // 4096
constexpr int QKVN  = 3 * C_D;        // 2304
constexpr int NCB   = C_V / 256;      // 125 col-blocks in LM head

typedef __bf16 bf16;
typedef __attribute__((ext_vector_type(8))) __bf16 bf16x8;
typedef __attribute__((ext_vector_type(4))) __bf16 bf16x4;
typedef __attribute__((ext_vector_type(4))) float  f32x4;
typedef __attribute__((ext_vector_type(4))) short  s16x4;

static __device__ __forceinline__ void gload16(const void* g, void* l) {
  __builtin_amdgcn_global_load_lds((const __attribute__((address_space(1))) void*)g,
                                   (__attribute__((address_space(3))) void*)l,
                                   16, 0, 0);
}

// ---------------- embedding ----------------
__global__ __launch_bounds__(256) void embed_kernel(const int* __restrict__ idx,
    const float* __restrict__ tok, const float* __restrict__ pos, float* __restrict__ x) {
  int gid = blockIdx.x * 256 + threadIdx.x;
  int row = gid / C_D, d = gid - row * C_D;
  int t = row & (C_T - 1);
  x[gid] = tok[(long)idx[row] * C_D + d] + pos[(long)t * C_D + d];
}

// ---------------- layernorm: 1 row per wave, 8 waves/block ----------------
__global__ __launch_bounds__(512) void ln_kernel(const float* __restrict__ x,
    const float* __restrict__ g, const float* __restrict__ bb, long goff,
    bf16* __restrict__ out) {
  int wv = threadIdx.x >> 6, lane = threadIdx.x & 63;
  long row = (long)blockIdx.x * 8 + wv;
  const float* xr = x + row * C_D;
  f32x4 v[3];
#pragma unroll
  for (int j = 0; j < 3; ++j)
    v[j] = *(const f32x4*)(xr + lane * 4 + j * 256);
  float s = 0.f, s2 = 0.f;
#pragma unroll
  for (int j = 0; j < 3; ++j)
#pragma unroll
    for (int q = 0; q < 4; ++q) { float t = v[j][q]; s += t; s2 += t * t; }
#pragma unroll
  for (int off = 32; off > 0; off >>= 1) {
    s  += __shfl_down(s, off);
    s2 += __shfl_down(s2, off);
  }
  s  = __shfl(s, 0);
  s2 = __shfl(s2, 0);
  float mean = s * (1.f / C_D);
  float var  = s2 * (1.f / C_D) - mean * mean;
  float rstd = rsqrtf(var + 1e-5f);
  bf16* orow = out + row * C_D;
#pragma unroll
  for (int j = 0; j < 3; ++j) {
    f32x4 gv = *(const f32x4*)(g  + goff + lane * 4 + j * 256);
    f32x4 bv = *(const f32x4*)(bb + goff + lane * 4 + j * 256);
    bf16x4 o;
#pragma unroll
    for (int q = 0; q < 4; ++q)
      o[q] = (bf16)((v[j][q] - mean) * rstd * gv[q] + bv[q]);
    *(bf16x4*)(orow + lane * 4 + j * 256) = o;
  }
}

// ---------------- generic tiled transpose+convert (Wlm) ----------------
__global__ __launch_bounds__(256) void transpose_kernel(const float* __restrict__ src,
    bf16* __restrict__ dst, int K, int N, long soff0, int ntn) {
  __shared__ bf16 tile[32][33];
  const float* s = src + soff0;
  int tn = blockIdx.x % ntn, tk = blockIdx.x / ntn;
  int c = threadIdx.x & 31, r = threadIdx.x >> 5;
#pragma unroll
  for (int it = 0; it < 4; ++it)
    tile[r + 8 * it][c] = (bf16)s[(long)(tk * 32 + r + 8 * it) * N + tn * 32 + c];
  __syncthreads();
#pragma unroll
  for (int it = 0; it < 4; ++it)
    dst[(long)(tn * 32 + r + 8 * it) * K + tk * 32 + c] = tile[c][r + 8 * it];
}

// ---------------- per-layer weight transposes: 8 tiles per block ----------------
__global__ __launch_bounds__(256) void transpose_layer_kernel(
    const float* __restrict__ Wq, const float* __restrict__ Wk,
    const float* __restrict__ Wv, const float* __restrict__ Wo,
    const float* __restrict__ W1, const float* __restrict__ W2,
    bf16* __restrict__ wqkvt, bf16* __restrict__ wot,
    bf16* __restrict__ w1t, bf16* __restrict__ w2t, int l) {
  __shared__ bf16 tile[32][33];
  int c = threadIdx.x & 31, r = threadIdx.x >> 5;
  for (int sub = 0; sub < 8; ++sub) {
    int bid = blockIdx.x * 8 + sub;
    const float* src; bf16* dst; int K, N, ntn, t;
    if (bid < 1728) {
      int which = bid / 576, rr = bid % 576, head = rr / 48;
      t = rr % 48;
      const float* W = which == 0 ? Wq : which == 1 ? Wk : Wv;
      src = W + (long)l * C_H * C_D * C_HS + (long)head * C_D * C_HS;
      dst = wqkvt + (long)which * C_D * C_D + (long)head * C_HS * C_D;
      K = C_D; N = C_HS; ntn = 2;
    } else if (bid < 2304) {
      t = bid - 1728; src = Wo + (long)l * C_D * C_D; dst = wot;
      K = C_D; N = C_D; ntn = 24;
    } else if (bid < 4608) {
      t = bid - 2304; src = W1 + (long)l * C_D * C_FF; dst = w1t;
      K = C_D; N = C_FF; ntn = 96;
    } else {
      t = bid - 4608; src = W2 + (long)l * C_FF * C_D; dst = w2t;
      K = C_FF; N = C_D; ntn = 24;
    }
    int tn = t % ntn, tk = t / ntn;
#pragma unroll
    for (int it = 0; it < 4; ++it)
      tile[r + 8 * it][c] = (bf16)src[(long)(tk * 32 + r + 8 * it) * N + tn * 32 + c];
    __syncthreads();
#pragma unroll
    for (int it = 0; it < 4; ++it)
      dst[(long)(tn * 32 + r + 8 * it) * K + tk * 32 + c] = tile[c][r + 8 * it];
    __syncthreads();
  }
}

// ================= 256x256 BK=64 8-wave GEMM (LM head) =================
// Phase-pipelined K-loop (T3+T4): 4 quadrant-phases per K-tile, half-tile
// staged per phase in order [B0,B1,A0,A1], counted vmcnt gates (never 0 in
// steady state) + barrier per phase. fp32 out + bias + fused loss partials.
__global__ __launch_bounds__(512) void gemm256(const bf16* __restrict__ A,
    const bf16* __restrict__ Bt, const float* __restrict__ bias, long boff,
    float* __restrict__ outp, float* __restrict__ lossp, int N, int K) {
  __shared__ __attribute__((aligned(16))) char smem[131072];
  int tid = threadIdx.x;
  int l = tid & 63, w = tid >> 6;
  int wm = w >> 2, wn = w & 3;
  int lg = l >> 4, lr = l & 15;

  int nwg = gridDim.x;
  int fid = blockIdx.x;
  int swz = (fid & 7) * (nwg >> 3) + (fid >> 3);
  long row0 = (long)(swz & 15) * 256;
  long col0 = (long)(swz >> 4) * 256;
  int cbi = (int)(col0 >> 8);

  int Y0 = tid * 16, Y1 = 8192 + tid * 16;
  auto dec = [](int Y, int& R, int& C) {
    int s = Y >> 10, y = Y & 1023;
    int r15 = y >> 6, z = y & 63;
    int q = (z ^ ((r15 & 8) << 2)) >> 4;
    R = (s >> 1) * 16 + r15;
    C = (s & 1) * 32 + q * 8;
  };
  int R0, C0, R1, C1;
  dec(Y0, R0, C0);  dec(Y1, R1, C1);
  const bf16* Ab = A  + row0 * K;
  const bf16* Bb = Bt + col0 * K;

  // one half-tile (16 KB): hsel 0=B-half0, 1=B-half1, 2=A-half0, 3=A-half1
  auto stageH = [&](int d, int kt, int hsel) {
    char* bb = smem + d * 65536;
    long kc = (long)kt * 64;
    if (hsel == 0) {
      gload16(Bb + (long)R0 * K + kc + C0, bb + 32768 + Y0);
      gload16(Bb + (long)R1 * K + kc + C1, bb + 32768 + Y1);
    } else if (hsel == 1) {
      gload16(Bb + (long)(128 + R0) * K + kc + C0, bb + 49152 + Y0);
      gload16(Bb + (long)(128 + R1) * K + kc + C1, bb + 49152 + Y1);
    } else if (hsel == 2) {
      gload16(Ab + (long)R0 * K + kc + C0, bb + Y0);
      gload16(Ab + (long)R1 * K + kc + C1, bb + Y1);
    } else {
      gload16(Ab + (long)(128 + R0) * K + kc + C0, bb + 16384 + Y0);
      gload16(Ab + (long)(128 + R1) * K + kc + C1, bb + 16384 + Y1);
    }
  };

  f32x4 acc[8][4];
  const f32x4 fz = {0.f, 0.f, 0.f, 0.f};
#pragma unroll
  for (int mf = 0; mf < 8; ++mf)
#pragma unroll
    for (int nf = 0; nf < 4; ++nf) acc[mf][nf] = fz;

  int aoff = lr * 64 + ((lg * 16) ^ ((lr & 8) << 2));
  int nk = K >> 6;

  // prologue: stage tile 0 (order B0,B1,A0,A1); gate B0,B1,A0 landed
  stageH(0, 0, 0); stageH(0, 0, 1); stageH(0, 0, 2); stageH(0, 0, 3);
  asm volatile("s_waitcnt vmcnt(2)" ::: "memory");
  __builtin_amdgcn_s_barrier();
  asm volatile("" ::: "memory");

  int d = 0;
  for (int kt = 0; kt < nk; ++kt) {
    bool last = (kt + 1 == nk);
#pragma unroll
    for (int p = 0; p < 4; ++p) {
      // ---- ds_reads for quadrant p (m-frags 2p,2p+1; A-half = p>>1) ----
      const char* aB = smem + d * 65536 + (p >> 1) * 16384;
      const char* bB = smem + d * 65536 + 32768 + (wn >> 1) * 16384;
      bf16x8 bfrag[4][2], af[2][2];
#pragma unroll
      for (int nf = 0; nf < 4; ++nf)
#pragma unroll
        for (int k = 0; k < 2; ++k)
          bfrag[nf][k] = *(const bf16x8*)(bB + ((((wn & 1) * 4 + nf) * 2 + k) << 10) + aoff);
#pragma unroll
      for (int mi = 0; mi < 2; ++mi)
#pragma unroll
        for (int k = 0; k < 2; ++k) {
          int f = p * 2 + mi;                 // f>>2 == p>>1 (half)
          af[mi][k] = *(const bf16x8*)(aB + ((((wm * 4 + (f & 3)) * 2 + k)) << 10) + aoff);
        }
      // ---- issue next tile's half-tile p (stays in flight across barriers) ----
      if (!last) stageH(d ^ 1, kt + 1, p);
      // ---- MFMA cluster ----
      __builtin_amdgcn_s_setprio(1);
#pragma unroll
      for (int mi = 0; mi < 2; ++mi)
#pragma unroll
        for (int nf = 0; nf < 4; ++nf)
#pragma unroll
          for (int k = 0; k < 2; ++k)
            acc[p * 2 + mi][nf] = __builtin_amdgcn_mfma_f32_16x16x32_bf16(
                af[mi][k], bfrag[nf][k], acc[p * 2 + mi][nf], 0, 0, 0);
      __builtin_amdgcn_s_setprio(0);
      // ---- end-of-phase gate for the NEXT phase's data, then barrier ----
      if (p == 1) {                // next phase reads A-half1(kt)
        if (last) asm volatile("s_waitcnt vmcnt(0)" ::: "memory");
        else      asm volatile("s_waitcnt vmcnt(4)" ::: "memory");
      } else if (p == 3 && !last) {// next phase reads B0,B1,A0 of kt+1
        asm volatile("s_waitcnt vmcnt(2)" ::: "memory");
      }
      __builtin_amdgcn_s_barrier();
      asm volatile("" ::: "memory");
    }
    d ^= 1;
  }
  __syncthreads();   // staging done; reuse smem for C repack

  // ---- epilogue: two 128-row passes, all 8 waves fill 4 frags each pass ----
#pragma unroll
  for (int h = 0; h < 2; ++h) {
    if (h) __syncthreads();
    float* lf = (float*)smem;   // [128][256] fp32 = 128 KB
#pragma unroll
    for (int fq = 0; fq < 4; ++fq) {
      int f = h * 4 + fq;
      int rl = wm * 64 + fq * 16 + lg * 4;
#pragma unroll
      for (int nf = 0; nf < 4; ++nf) {
        int col = wn * 64 + nf * 16 + lr;
        float bv = bias ? bias[boff + col0 + col] : 0.f;
#pragma unroll
        for (int r = 0; r < 4; ++r)
          lf[(rl + r) * 256 + col] = acc[f][nf][r] + bv;
      }
    }
    __syncthreads();
#pragma unroll
    for (int it = 0; it < 16; ++it) {
      int byte = it * 8192 + tid * 16;
      int rl = byte >> 10, cb = byte & 1023;
      *(f32x4*)(outp + (row0 + h * 128 + rl) * N + col0 + (cb >> 2)) =
          *(const f32x4*)(smem + byte);
    }
    if (lossp) {
      const float* lfc = (const float*)smem;
      int row = tid >> 2, chunk = tid & 3;
      float M = -1e30f, S = 0.f;
#pragma unroll
      for (int j = 0; j < 16; ++j) {
        int jj = (j + row) & 15;
        f32x4 v = *(const f32x4*)(lfc + row * 256 + chunk * 64 + jj * 4);
#pragma unroll
        for (int q = 0; q < 4; ++q) {
          float xv = v[q];
          if (xv > M) { S *= __expf(M - xv); M = xv; }
          S += __expf(xv - M);
        }
      }
#pragma unroll
      for (int off = 1; off < 4; off <<= 1) {
        float Mo = __shfl_xor(M, off), So = __shfl_xor(S, off);
        float Mn = fmaxf(M, Mo);
        S = S * __expf(M - Mn) + So * __expf(Mo - Mn);
        M = Mn;
      }
      if (chunk == 0) {
        long pi = ((row0 + h * 128 + row) * NCB + cbi) * 2;
        lossp[pi] = M;  lossp[pi + 1] = S;
      }
    }
  }
}

// ---------------- 128x128 GEMM: modes 0 bf16+bias / 1 relu (QKV, FF1) ----------------
template <int MODE>
__global__ __launch_bounds__(256) void gemm_bt(const bf16* __restrict__ A,
    const bf16* __restrict__ Bt, const float* __restrict__ bias, long boff,
    void* __restrict__ outp, int N, int K) {
  __shared__ __attribute__((aligned(16))) char smem[32768];
  int tid = threadIdx.x;
  int l = tid & 63;
  int w = tid >> 6, wr = w >> 1, wc = w & 1;
  int lg = l >> 4, lr = l & 15;

  int nwg = gridDim.x;
  int fid = blockIdx.x;
  int swz = (fid & 7) * (nwg >> 3) + (fid >> 3);
  long row0 = (long)(swz & 31) * 128;
  long col0 = (long)(swz >> 5) * 128;

  const bf16* ga = A  + (row0 + (tid >> 2)) * K + (tid & 3) * 8;
  const bf16* gb = Bt + (col0 + (tid >> 2)) * K + (tid & 3) * 8;

  f32x4 acc[4][4];
  const f32x4 fz = {0.f, 0.f, 0.f, 0.f};
#pragma unroll
  for (int m = 0; m < 4; ++m)
#pragma unroll
    for (int n = 0; n < 4; ++n) acc[m][n] = fz;

  int nk = K >> 5;
  {
    bf16* la = (bf16*)smem + tid * 8;
    bf16* lb = (bf16*)(smem + 8192) + tid * 8;
    gload16(ga, la);  gload16(ga + (long)64 * K, la + 2048);
    gload16(gb, lb);  gload16(gb + (long)64 * K, lb + 2048);
    ga += 32; gb += 32;
  }
  int cur = 0;
  for (int t = 0; t < nk; ++t) {
    __syncthreads();
    if (t + 1 < nk) {
      char* bufb = smem + (cur ^ 1) * 16384;
      bf16* la = (bf16*)bufb + tid * 8;
      bf16* lb = (bf16*)(bufb + 8192) + tid * 8;
      gload16(ga, la);  gload16(ga + (long)64 * K, la + 2048);
      gload16(gb, lb);  gload16(gb + (long)64 * K, lb + 2048);
      ga += 32; gb += 32;
    }
    const bf16* cA = (const bf16*)(smem + cur * 16384);
    const bf16* cB = (const bf16*)(smem + cur * 16384 + 8192);
    bf16x8 af[4], bfr[4];
#pragma unroll
    for (int m = 0; m < 4; ++m)
      af[m] = *(const bf16x8*)(cA + (wr * 64 + m * 16 + lr) * 32 + lg * 8);
#pragma unroll
    for (int n = 0; n < 4; ++n)
      bfr[n] = *(const bf16x8*)(cB + (wc * 64 + n * 16 + lr) * 32 + lg * 8);
#pragma unroll
    for (int m = 0; m < 4; ++m)
#pragma unroll
      for (int n = 0; n < 4; ++n)
        acc[m][n] = __builtin_amdgcn_mfma_f32_16x16x32_bf16(af[m], bfr[n], acc[m][n], 0, 0, 0);
    cur ^= 1;
  }
  __syncthreads();

  bf16* lc = (bf16*)smem;
#pragma unroll
  for (int n = 0; n < 4; ++n) {
    int gcl = wc * 64 + n * 16 + lr;
    float bv = bias ? bias[boff + col0 + gcl] : 0.f;
#pragma unroll
    for (int m = 0; m < 4; ++m) {
      int rb = wr * 64 + m * 16 + lg * 4;
#pragma unroll
      for (int r = 0; r < 4; ++r) {
        float v = acc[m][n][r] + bv;
        if (MODE == 1) v = fmaxf(v, 0.f);
        lc[(rb + r) * 128 + gcl] = (bf16)v;
      }
    }
  }
  __syncthreads();
#pragma unroll
  for (int it = 0; it < 8; ++it) {
    int byte = it * 4096 + tid * 16;
    int rl = byte >> 8;
    int cb = byte & 255;
    *(bf16x8*)((bf16*)outp + (row0 + rl) * N + col0 + (cb >> 1)) =
        *(const bf16x8*)(smem + byte);
  }
}

// ---------------- 128x64 GEMM, fp32 resid += (Wo, FF2) ----------------
__global__ __launch_bounds__(256) void gemm_bt64(const bf16* __restrict__ A,
    const bf16* __restrict__ Bt, const float* __restrict__ bias, long boff,
    float* __restrict__ resid, int N, int K) {
  __shared__ __attribute__((aligned(16))) char smem[32768];
  int tid = threadIdx.x;
  int l = tid & 63;
  int w = tid >> 6, wr = w >> 1, wc = w & 1;
  int lg = l >> 4, lr = l & 15;

  int nwg = gridDim.x;
  int fid = blockIdx.x;
  int swz = (fid & 7) * (nwg >> 3) + (fid >> 3);
  long row0 = (long)(swz & 31) * 128;
  long col0 = (long)(swz >> 5) * 64;

  const bf16* ga = A  + (row0 + (tid >> 2)) * K + (tid & 3) * 8;
  const bf16* gb = Bt + (col0 + (tid >> 2)) * K + (tid & 3) * 8;

  f32x4 acc[4][2];
  const f32x4 fz = {0.f, 0.f, 0.f, 0.f};
#pragma unroll
  for (int m = 0; m < 4; ++m)
#pragma unroll
    for (int n = 0; n < 2; ++n) acc[m][n] = fz;

  int nk = K >> 5;
  {
    bf16* la = (bf16*)smem + tid * 8;
    bf16* lb = (bf16*)(smem + 8192) + tid * 8;
    gload16(ga, la);  gload16(ga + (long)64 * K, la + 2048);
    gload16(gb, lb);
    ga += 32; gb += 32;
  }
  int cur = 0;
  for (int t = 0; t < nk; ++t) {
    __syncthreads();
    if (t + 1 < nk) {
      char* bufb = smem + (cur ^ 1) * 12288;
      bf16* la = (bf16*)bufb + tid * 8;
      bf16* lb = (bf16*)(bufb + 8192) + tid * 8;
      gload16(ga, la);  gload16(ga + (long)64 * K, la + 2048);
      gload16(gb, lb);
      ga += 32; gb += 32;
    }
    const bf16* cA = (const bf16*)(smem + cur * 12288);
    const bf16* cB = (const bf16*)(smem + cur * 12288 + 8192);
    bf16x8 af[4], bfr[2];
#pragma unroll
    for (int m = 0; m < 4; ++m)
      af[m] = *(const bf16x8*)(cA + (wr * 64 + m * 16 + lr) * 32 + lg * 8);
#pragma unroll
    for (int n = 0; n < 2; ++n)
      bfr[n] = *(const bf16x8*)(cB + (wc * 32 + n * 16 + lr) * 32 + lg * 8);
#pragma unroll
    for (int m = 0; m < 4; ++m)
#pragma unroll
      for (int n = 0; n < 2; ++n)
        acc[m][n] = __builtin_amdgcn_mfma_f32_16x16x32_bf16(af[m], bfr[n], acc[m][n], 0, 0, 0);
    cur ^= 1;
  }
  __syncthreads();

  float* lcf = (float*)smem;
#pragma unroll
  for (int n = 0; n < 2; ++n) {
    int col = wc * 32 + n * 16 + lr;
    float bv = bias ? bias[boff + col0 + col] : 0.f;
#pragma unroll
    for (int m = 0; m < 4; ++m) {
      int rl = wr * 64 + m * 16 + lg * 4;
#pragma unroll
      for (int r = 0; r < 4; ++r)
        lcf[(rl + r) * 64 + col] = acc[m][n][r] + bv;
    }
  }
  __syncthreads();
#pragma unroll
  for (int it = 0; it < 8; ++it) {
    int byte = it * 4096 + tid * 16;
    int rl = byte >> 8;
    int cb = byte & 255;
    long gr = row0 + rl;
    f32x4 v = *(const f32x4*)(smem + byte);
    f32x4 g = *(const f32x4*)(resid + gr * N + col0 + (cb >> 2));
    v += g;
    *(f32x4*)(resid + gr * N + col0 + (cb >> 2)) = v;
  }
}

// ---------------- flash attention: KVBLK=32 ----------------
#define TRRD(D, OFF) asm volatile("ds_read_b64_tr_b16 %0, %1 offset:" OFF \
                                  : "=v"(D) : "v"(trp))
__global__ __launch_bounds__(64) void attn_kernel(const bf16* __restrict__ qkv,
                                                  bf16* __restrict__ attout) {
  int fid = blockIdx.x;
  int swzb = (fid & 7) * 384 + (fid >> 3);
  int qt = swzb & 63;
  int bh = swzb >> 6;
  int b = bh / C_H, h = bh % C_H;
  int l = threadIdx.x;
  int lg = l >> 4, lr = l & 15;
  const bf16* base = qkv + (long)b * C_T * QKVN;

  const bf16* qp = base + (long)(qt * 16 + lr) * QKVN + h * C_HS;
  bf16x8 qf0 = *(const bf16x8*)(qp + lg * 8);
  bf16x8 qf1 = *(const bf16x8*)(qp + 32 + lg * 8);

  const f32x4 fz = {0.f, 0.f, 0.f, 0.f};
  f32x4 o[4] = {fz, fz, fz, fz};
  float m_run[4], l_run[4];
#pragma unroll
  for (int r = 0; r < 4; ++r) { m_run[r] = -1e30f; l_run[r] = 0.f; }

  __shared__ __attribute__((aligned(16))) bf16 p_lds[16][40];
  __shared__ __attribute__((aligned(16))) bf16 vt_sub[2048];

  unsigned trp = (unsigned)(unsigned long)
      ((const __attribute__((address_space(3))) char*)vt_sub + l * 8);

  int nkt = (qt * 16 + 15) / 32 + 1;
  for (int kt = 0; kt < nkt; ++kt) {
    int key0 = kt * 32;
    f32x4 sacc[2];
#pragma unroll
    for (int ss = 0; ss < 2; ++ss) {
      const bf16* kp = base + (long)(key0 + ss * 16 + lr) * QKVN + C_D + h * C_HS;
      bf16x8 kf0 = *(const bf16x8*)(kp + lg * 8);
      bf16x8 kf1 = *(const bf16x8*)(kp + 32 + lg * 8);
      f32x4 a = fz;
      a = __builtin_amdgcn_mfma_f32_16x16x32_bf16(qf0, kf0, a, 0, 0, 0);
      a = __builtin_amdgcn_mfma_f32_16x16x32_bf16(qf1, kf1, a, 0, 0, 0);
      sacc[ss] = a;
    }
#pragma unroll
    for (int r = 0; r < 4; ++r) {
      int qrow = qt * 16 + lg * 4 + r;
      bool u0 = (key0 + lr) <= qrow;
      bool u1 = (key0 + 16 + lr) <= qrow;
      float s0 = u0 ? sacc[0][r] * 0.125f : -1e30f;
      float s1 = u1 ? sacc[1][r] * 0.125f : -1e30f;
      float mr = fmaxf(s0, s1);
      mr = fmaxf(mr, __shfl_xor(mr, 1));
      mr = fmaxf(mr, __shfl_xor(mr, 2));
      mr = fmaxf(mr, __shfl_xor(mr, 4));
      mr = fmaxf(mr, __shfl_xor(mr, 8));
      float mnew = fmaxf(m_run[r], mr);
      float scale = __expf(m_run[r] - mnew);
      float p0 = u0 ? __expf(s0 - mnew) : 0.f;
      float p1 = u1 ? __expf(s1 - mnew) : 0.f;
      float rs = p0 + p1;
      rs += __shfl_xor(rs, 1);
      rs += __shfl_xor(rs, 2);
      rs += __shfl_xor(rs, 4);
      rs += __shfl_xor(rs, 8);
      l_run[r] = l_run[r] * scale + rs;
      m_run[r] = mnew;
      o[0][r] *= scale; o[1][r] *= scale; o[2][r] *= scale; o[3][r] *= scale;
      p_lds[lg * 4 + r][lr]      = (bf16)p0;
      p_lds[lg * 4 + r][16 + lr] = (bf16)p1;
    }
#pragma unroll
    for (int it = 0; it < 4; ++it) {
      int kl = it * 8 + (l >> 3);
      int d0 = (l & 7) * 8;
      bf16x8 vv = *(const bf16x8*)(base + (long)(key0 + kl) * QKVN + 2 * C_D + h * C_HS + d0);
      int ba = ((d0 >> 4) << 10) + (((kl >> 2) & 1) << 9) + ((kl >> 3) << 7)
             + ((kl & 3) << 5) + ((d0 & 15) << 1);
      *(bf16x8*)((char*)vt_sub + ba) = vv;
    }
    __syncthreads();
    s16x4 t0a, t0b, t1a, t1b, t2a, t2b, t3a, t3b;
    TRRD(t0a, "0");    TRRD(t0b, "512");
    TRRD(t1a, "1024"); TRRD(t1b, "1536");
    TRRD(t2a, "2048"); TRRD(t2b, "2560");
    TRRD(t3a, "3072"); TRRD(t3b, "3584");
    bf16x8 pf = *(const bf16x8*)(&p_lds[lr][lg * 8]);
    asm volatile("s_waitcnt lgkmcnt(0)" ::: "memory");
    __builtin_amdgcn_sched_barrier(0);
    union uu { short s[8]; bf16x8 v; };
    auto mk = [](s16x4 a, s16x4 bq) {
      uu u;
      u.s[0] = a[0]; u.s[1] = a[1]; u.s[2] = a[2]; u.s[3] = a[3];
      u.s[4] = bq[0]; u.s[5] = bq[1]; u.s[6] = bq[2]; u.s[7] = bq[3];
      return u.v;
    };
    o[0] = __builtin_amdgcn_mfma_f32_16x16x32_bf16(pf, mk(t0a, t0b), o[0], 0, 0, 0);
    o[1] = __builtin_amdgcn_mfma_f32_16x16x32_bf16(pf, mk(t1a, t1b), o[1], 0, 0, 0);
    o[2] = __builtin_amdgcn_mfma_f32_16x16x32_bf16(pf, mk(t2a, t2b), o[2], 0, 0, 0);
    o[3] = __builtin_amdgcn_mfma_f32_16x16x32_bf16(pf, mk(t3a, t3b), o[3], 0, 0, 0);
    __syncthreads();
  }
#pragma unroll
  for (int c = 0; c < 4; ++c)
#pragma unroll
    for (int r = 0; r < 4; ++r) {
      int qrow = qt * 16 + lg * 4 + r;
      attout[((long)b * C_T + qrow) * C_D + h * C_HS + c * 16 + lr] =
          (bf16)(o[c][r] / l_run[r]);
    }
}

// ---------------- loss from partials ----------------
__global__ __launch_bounds__(128) void loss_partial_kernel(const float* __restrict__ lossp,
    const float* __restrict__ logits, const int* __restrict__ targets,
    float* __restrict__ rowloss) {
  int row = blockIdx.x * 128 + threadIdx.x;
  const float* pp = lossp + (long)row * NCB * 2;
  float M = -1e30f, S = 0.f;
  for (int i = 0; i < NCB; ++i) {
    float pm = pp[i * 2], ps = pp[i * 2 + 1];
    float Mn = fmaxf(M, pm);
    S = S * __expf(M - Mn) + ps * __expf(pm - Mn);
    M = Mn;
  }
  float lt = logits[(long)row * C_V + targets[row]];
  rowloss[row] = -(lt - M - logf(S));
}

__global__ __launch_bounds__(256) void loss_final(const float* __restrict__ rowloss,
                                                  float* __restrict__ out) {
  int tid = threadIdx.x;
  float s = 0.f;
  for (int i = tid; i < ROWS; i += 256) s += rowloss[i];
#pragma unroll
  for (int off = 32; off > 0; off >>= 1) s += __shfl_down(s, off);
  __shared__ float sm[4];
  if ((tid & 63) == 0) sm[tid >> 6] = s;
  __syncthreads();
  if (tid == 0) out[0] = (sm[0] + sm[1] + sm[2] + sm[3]) * (1.f / ROWS);
}

// ---------------- launch ----------------
extern "C" void kernel_launch(void* const* d_in, const int* in_sizes, int n_in,
                              void* d_out, int out_size, void* d_ws, size_t ws_size,
                              hipStream_t stream) {
  (void)in_sizes; (void)n_in; (void)out_size; (void)ws_size;
  const int*   idx     = (const int*)  d_in[0];
  const int*   targets = (const int*)  d_in[1];
  const float* tok     = (const float*)d_in[2];
  const float* pos     = (const float*)d_in[3];
  const float* Wq      = (const float*)d_in[4];
  const float* Wk      = (const float*)d_in[5];
  const float* Wv      = (const float*)d_in[6];
  const float* Wo      = (const float*)d_in[7];
  const float* bo      = (const float*)d_in[8];
  const float* W1      = (const float*)d_in[9];
  const float* b1      = (const float*)d_in[10];
  const float* W2      = (const float*)d_in[11];
  const float* b2      = (const float*)d_in[12];
  const float* ln1g    = (const float*)d_in[13];
  const float* ln1b    = (const float*)d_in[14];
  const float* ln2g    = (const float*)d_in[15];
  const float* ln2b    = (const float*)d_in[16];
  const float* lnfg    = (const float*)d_in[17];
  const float* lnfb    = (const float*)d_in[18];
  const float* Wlm     = (const float*)d_in[19];
  const float* blm     = (const float*)d_in[20];

  char* p = (char*)d_ws;
  auto alloc = [&](size_t bytes) {
    char* r = p; p += (bytes + 255) & ~(size_t)255; return r;
  };
  float* x       = (float*)alloc((size_t)ROWS * C_D * 4);
  bf16*  h       = (bf16*) alloc((size_t)ROWS * C_D * 2);
  bf16*  qkv     = (bf16*) alloc((size_t)ROWS * QKVN * 2);   // \  reused as wlmt
  bf16*  attout  = (bf16*) alloc((size_t)ROWS * C_D * 2);    //  > after layer loop
  bf16*  ffbuf   = (bf16*) alloc((size_t)ROWS * C_FF * 2);   // /
  bf16*  wqkvt   = (bf16*) alloc((size_t)QKVN * C_D * 2);
  bf16*  wot     = (bf16*) alloc((size_t)C_D * C_D * 2);
  bf16*  w1t     = (bf16*) alloc((size_t)C_FF * C_D * 2);
  bf16*  w2t     = (bf16*) alloc((size_t)C_D * C_FF * 2);
  float* rowloss = (float*)alloc((size_t)ROWS * 4);
  float* lossp   = (float*)alloc((size_t)ROWS * NCB * 2 * 4);
  bf16*  wlmt    = qkv;   // alias: 49.15 MB needed, qkv+attout+ffbuf = 50.33 MB

  float* logits = (float*)d_out;

  embed_kernel<<<ROWS * C_D / 256, 256, 0, stream>>>(idx, tok, pos, x);

  for (int l = 0; l < C_L; ++l) {
    transpose_layer_kernel<<<864, 256, 0, stream>>>(
        Wq, Wk, Wv, Wo, W1, W2, wqkvt, wot, w1t, w2t, l);

    ln_kernel<<<ROWS / 8, 512, 0, stream>>>(x, ln1g, ln1b, (long)l * C_D, h);
    gemm_bt<0><<<(QKVN / 128) * 32, 256, 0, stream>>>(
        h, wqkvt, nullptr, 0, qkv, QKVN, C_D);
    attn_kernel<<<C_B * C_H * (C_T / 16), 64, 0, stream>>>(qkv, attout);
    gemm_bt64<<<(C_D / 64) * 32, 256, 0, stream>>>(
        attout, wot, bo, (long)l * C_D, x, C_D, C_D);
    ln_kernel<<<ROWS / 8, 512, 0, stream>>>(x, ln2g, ln2b, (long)l * C_D, h);
    gemm_bt<1><<<(C_FF / 128) * 32, 256, 0, stream>>>(
        h, w1t, b1, (long)l * C_FF, ffbuf, C_FF, C_D);
    gemm_bt64<<<(C_D / 64) * 32, 256, 0, stream>>>(
        ffbuf, w2t, b2, (long)l * C_D, x, C_D, C_FF);
  }

  transpose_kernel<<<(C_V / 32) * (C_D / 32), 256, 0, stream>>>(
      Wlm, wlmt, C_D, C_V, 0, C_V / 32);

  ln_kernel<<<ROWS / 8, 512, 0, stream>>>(x, lnfg, lnfb, 0, h);
  gemm256<<<16 * (C_V / 256), 512, 0, stream>>>(
      h, wlmt, blm, 0, logits, lossp, C_V, C_D);
  loss_partial_kernel<<<ROWS / 128, 128, 0, stream>>>(lossp, logits, targets, rowloss);
  loss_final<<<1, 256, 0, stream>>>(rowloss, logits + (long)ROWS * C_V);
}

// Round 16
// 2766.079 us; speedup vs baseline: 1.0467x; 1.0125x over previous
//
#include <hip/hip_runtime.h>

// ---------------- constants ----------------
constexpr int C_B   = 4;
constexpr int C_T   = 1024;
constexpr int C_D   = 768;
constexpr int C_H   = 12;
constexpr int C_HS  = 64;
constexpr int C_FF  = 3072;
constexpr int C_V   = 32000;
constexpr int C_L   = 12;
constexpr int ROWS  = C_B * C_T;      // 4096
constexpr int QKVN  = 3 * C_D;        // 2304
constexpr int NCB   = C_V / 256;      // 125 col-blocks in LM head

typedef __bf16 bf16;
typedef __attribute__((ext_vector_type(8))) __bf16 bf16x8;
typedef __attribute__((ext_vector_type(4))) __bf16 bf16x4;
typedef __attribute__((ext_vector_type(4))) float  f32x4;
typedef __attribute__((ext_vector_type(4))) short  s16x4;

static __device__ __forceinline__ void gload16(const void* g, void* l) {
  __builtin_amdgcn_global_load_lds((const __attribute__((address_space(1))) void*)g,
                                   (__attribute__((address_space(3))) void*)l,
                                   16, 0, 0);
}

// ---------------- embedding: bf16 residual ----------------
__global__ __launch_bounds__(256) void embed_kernel(const int* __restrict__ idx,
    const float* __restrict__ tok, const float* __restrict__ pos, bf16* __restrict__ x) {
  int gid = blockIdx.x * 256 + threadIdx.x;
  int row = gid / C_D, d = gid - row * C_D;
  int t = row & (C_T - 1);
  x[gid] = (bf16)(tok[(long)idx[row] * C_D + d] + pos[(long)t * C_D + d]);
}

// ---------------- layernorm: bf16 x in, bf16 out; 1 row/wave ----------------
__global__ __launch_bounds__(512) void ln_kernel(const bf16* __restrict__ x,
    const float* __restrict__ g, const float* __restrict__ bb, long goff,
    bf16* __restrict__ out) {
  int wv = threadIdx.x >> 6, lane = threadIdx.x & 63;
  long row = (long)blockIdx.x * 8 + wv;
  const bf16* xr = x + row * C_D;
  float v[12];
#pragma unroll
  for (int j = 0; j < 3; ++j) {
    bf16x4 b4 = *(const bf16x4*)(xr + lane * 4 + j * 256);
#pragma unroll
    for (int q = 0; q < 4; ++q) v[j * 4 + q] = (float)b4[q];
  }
  float s = 0.f, s2 = 0.f;
#pragma unroll
  for (int j = 0; j < 12; ++j) { s += v[j]; s2 += v[j] * v[j]; }
#pragma unroll
  for (int off = 32; off > 0; off >>= 1) {
    s  += __shfl_down(s, off);
    s2 += __shfl_down(s2, off);
  }
  s  = __shfl(s, 0);
  s2 = __shfl(s2, 0);
  float mean = s * (1.f / C_D);
  float var  = s2 * (1.f / C_D) - mean * mean;   // biased var, matches reference
  float rstd = rsqrtf(var + 1e-5f);
  bf16* orow = out + row * C_D;
#pragma unroll
  for (int j = 0; j < 3; ++j) {
    f32x4 gv = *(const f32x4*)(g  + goff + lane * 4 + j * 256);
    f32x4 bv = *(const f32x4*)(bb + goff + lane * 4 + j * 256);
    bf16x4 o;
#pragma unroll
    for (int q = 0; q < 4; ++q)
      o[q] = (bf16)((v[j * 4 + q] - mean) * rstd * gv[q] + bv[q]);
    *(bf16x4*)(orow + lane * 4 + j * 256) = o;
  }
}

// ---------------- generic tiled transpose+convert (Wlm) ----------------
__global__ __launch_bounds__(256) void transpose_kernel(const float* __restrict__ src,
    bf16* __restrict__ dst, int K, int N, long soff0, int ntn) {
  __shared__ bf16 tile[32][33];
  const float* s = src + soff0;
  int tn = blockIdx.x % ntn, tk = blockIdx.x / ntn;
  int c = threadIdx.x & 31, r = threadIdx.x >> 5;
#pragma unroll
  for (int it = 0; it < 4; ++it)
    tile[r + 8 * it][c] = (bf16)s[(long)(tk * 32 + r + 8 * it) * N + tn * 32 + c];
  __syncthreads();
#pragma unroll
  for (int it = 0; it < 4; ++it)
    dst[(long)(tn * 32 + r + 8 * it) * K + tk * 32 + c] = tile[c][r + 8 * it];
}

// ---------------- per-layer weight transposes: 8 tiles per block ----------------
__global__ __launch_bounds__(256) void transpose_layer_kernel(
    const float* __restrict__ Wq, const float* __restrict__ Wk,
    const float* __restrict__ Wv, const float* __restrict__ Wo,
    const float* __restrict__ W1, const float* __restrict__ W2,
    bf16* __restrict__ wqkvt, bf16* __restrict__ wot,
    bf16* __restrict__ w1t, bf16* __restrict__ w2t, int l) {
  __shared__ bf16 tile[32][33];
  int c = threadIdx.x & 31, r = threadIdx.x >> 5;
  for (int sub = 0; sub < 8; ++sub) {
    int bid = blockIdx.x * 8 + sub;
    const float* src; bf16* dst; int K, N, ntn, t;
    if (bid < 1728) {
      int which = bid / 576, rr = bid % 576, head = rr / 48;
      t = rr % 48;
      const float* W = which == 0 ? Wq : which == 1 ? Wk : Wv;
      src = W + (long)l * C_H * C_D * C_HS + (long)head * C_D * C_HS;
      dst = wqkvt + (long)which * C_D * C_D + (long)head * C_HS * C_D;
      K = C_D; N = C_HS; ntn = 2;
    } else if (bid < 2304) {
      t = bid - 1728; src = Wo + (long)l * C_D * C_D; dst = wot;
      K = C_D; N = C_D; ntn = 24;
    } else if (bid < 4608) {
      t = bid - 2304; src = W1 + (long)l * C_D * C_FF; dst = w1t;
      K = C_D; N = C_FF; ntn = 96;
    } else {
      t = bid - 4608; src = W2 + (long)l * C_FF * C_D; dst = w2t;
      K = C_FF; N = C_D; ntn = 24;
    }
    int tn = t % ntn, tk = t / ntn;
#pragma unroll
    for (int it = 0; it < 4; ++it)
      tile[r + 8 * it][c] = (bf16)src[(long)(tk * 32 + r + 8 * it) * N + tn * 32 + c];
    __syncthreads();
#pragma unroll
    for (int it = 0; it < 4; ++it)
      dst[(long)(tn * 32 + r + 8 * it) * K + tk * 32 + c] = tile[c][r + 8 * it];
    __syncthreads();
  }
}

// ================= 256x256 BK=64 8-wave GEMM (LM head; plain 2-phase) =================
__global__ __launch_bounds__(512) void gemm256(const bf16* __restrict__ A,
    const bf16* __restrict__ Bt, const float* __restrict__ bias, long boff,
    float* __restrict__ outp, float* __restrict__ lossp, int N, int K) {
  __shared__ __attribute__((aligned(16))) char smem[131072];
  int tid = threadIdx.x;
  int l = tid & 63, w = tid >> 6;
  int wm = w >> 2, wn = w & 3;
  int lg = l >> 4, lr = l & 15;

  int nwg = gridDim.x;
  int fid = blockIdx.x;
  int swz = (fid & 7) * (nwg >> 3) + (fid >> 3);
  long row0 = (long)(swz & 15) * 256;
  long col0 = (long)(swz >> 4) * 256;
  int cbi = (int)(col0 >> 8);

  int Y0 = tid * 16, Y1 = 8192 + tid * 16;
  auto dec = [](int Y, int& R, int& C) {
    int s = Y >> 10, y = Y & 1023;
    int r15 = y >> 6, z = y & 63;
    int q = (z ^ ((r15 & 8) << 2)) >> 4;
    R = (s >> 1) * 16 + r15;
    C = (s & 1) * 32 + q * 8;
  };
  int R0, C0, R1, C1;
  dec(Y0, R0, C0);  dec(Y1, R1, C1);
  const bf16* Ab = A  + row0 * K;
  const bf16* Bb = Bt + col0 * K;

  auto stage = [&](int d, int kt) {
    char* bb = smem + d * 65536;
    long kc = (long)kt * 64;
    gload16(Ab + (long)R0 * K + kc + C0, bb + Y0);
    gload16(Ab + (long)R1 * K + kc + C1, bb + Y1);
    gload16(Ab + (long)(128 + R0) * K + kc + C0, bb + 16384 + Y0);
    gload16(Ab + (long)(128 + R1) * K + kc + C1, bb + 16384 + Y1);
    gload16(Bb + (long)R0 * K + kc + C0, bb + 32768 + Y0);
    gload16(Bb + (long)R1 * K + kc + C1, bb + 32768 + Y1);
    gload16(Bb + (long)(128 + R0) * K + kc + C0, bb + 49152 + Y0);
    gload16(Bb + (long)(128 + R1) * K + kc + C1, bb + 49152 + Y1);
  };

  f32x4 acc[8][4];
  const f32x4 fz = {0.f, 0.f, 0.f, 0.f};
#pragma unroll
  for (int mf = 0; mf < 8; ++mf)
#pragma unroll
    for (int nf = 0; nf < 4; ++nf) acc[mf][nf] = fz;

  int aoff = lr * 64 + ((lg * 16) ^ ((lr & 8) << 2));
  int nk = K >> 6;
  stage(0, 0);
  int d = 0;
  for (int kt = 0; kt < nk; ++kt) {
    __syncthreads();
    if (kt + 1 < nk) stage(d ^ 1, kt + 1);
    const char* bB = smem + d * 65536 + 32768 + (wn >> 1) * 16384;
    bf16x8 bfrag[4][2];
#pragma unroll
    for (int nf = 0; nf < 4; ++nf)
#pragma unroll
      for (int k = 0; k < 2; ++k)
        bfrag[nf][k] = *(const bf16x8*)(bB + ((((wn & 1) * 4 + nf) * 2 + k) << 10) + aoff);
#pragma unroll
    for (int p = 0; p < 4; ++p) {
      bf16x8 af[2][2];
#pragma unroll
      for (int mi = 0; mi < 2; ++mi)
#pragma unroll
        for (int k = 0; k < 2; ++k) {
          int f = p * 2 + mi;
          const char* aB = smem + d * 65536 + (f >> 2) * 16384;
          af[mi][k] = *(const bf16x8*)(aB + (((wm * 4 + (f & 3)) * 2 + k) << 10) + aoff);
        }
      __builtin_amdgcn_s_setprio(1);
#pragma unroll
      for (int mi = 0; mi < 2; ++mi)
#pragma unroll
        for (int nf = 0; nf < 4; ++nf)
#pragma unroll
          for (int k = 0; k < 2; ++k)
            acc[p * 2 + mi][nf] = __builtin_amdgcn_mfma_f32_16x16x32_bf16(
                af[mi][k], bfrag[nf][k], acc[p * 2 + mi][nf], 0, 0, 0);
      __builtin_amdgcn_s_setprio(0);
    }
    d ^= 1;
  }
  __syncthreads();

#pragma unroll
  for (int h = 0; h < 2; ++h) {
    if (h) __syncthreads();
    float* lf = (float*)smem;
#pragma unroll
    for (int fq = 0; fq < 4; ++fq) {
      int f = h * 4 + fq;
      int rl = wm * 64 + fq * 16 + lg * 4;
#pragma unroll
      for (int nf = 0; nf < 4; ++nf) {
        int col = wn * 64 + nf * 16 + lr;
        float bv = bias ? bias[boff + col0 + col] : 0.f;
#pragma unroll
        for (int r = 0; r < 4; ++r)
          lf[(rl + r) * 256 + col] = acc[f][nf][r] + bv;
      }
    }
    __syncthreads();
#pragma unroll
    for (int it = 0; it < 16; ++it) {
      int byte = it * 8192 + tid * 16;
      int rl = byte >> 10, cb = byte & 1023;
      *(f32x4*)(outp + (row0 + h * 128 + rl) * N + col0 + (cb >> 2)) =
          *(const f32x4*)(smem + byte);
    }
    if (lossp) {
      const float* lfc = (const float*)smem;
      int row = tid >> 2, chunk = tid & 3;
      float M = -1e30f, S = 0.f;
#pragma unroll
      for (int j = 0; j < 16; ++j) {
        int jj = (j + row) & 15;
        f32x4 v = *(const f32x4*)(lfc + row * 256 + chunk * 64 + jj * 4);
#pragma unroll
        for (int q = 0; q < 4; ++q) {
          float xv = v[q];
          if (xv > M) { S *= __expf(M - xv); M = xv; }
          S += __expf(xv - M);
        }
      }
#pragma unroll
      for (int off = 1; off < 4; off <<= 1) {
        float Mo = __shfl_xor(M, off), So = __shfl_xor(S, off);
        float Mn = fmaxf(M, Mo);
        S = S * __expf(M - Mn) + So * __expf(Mo - Mn);
        M = Mn;
      }
      if (chunk == 0) {
        long pi = ((row0 + h * 128 + row) * NCB + cbi) * 2;
        lossp[pi] = M;  lossp[pi + 1] = S;
      }
    }
  }
}

// ---------------- 128x128 GEMM: modes 0 bf16+bias / 1 relu (QKV, FF1) ----------------
template <int MODE>
__global__ __launch_bounds__(256) void gemm_bt(const bf16* __restrict__ A,
    const bf16* __restrict__ Bt, const float* __restrict__ bias, long boff,
    void* __restrict__ outp, int N, int K) {
  __shared__ __attribute__((aligned(16))) char smem[32768];
  int tid = threadIdx.x;
  int l = tid & 63;
  int w = tid >> 6, wr = w >> 1, wc = w & 1;
  int lg = l >> 4, lr = l & 15;

  int nwg = gridDim.x;
  int fid = blockIdx.x;
  int swz = (fid & 7) * (nwg >> 3) + (fid >> 3);
  long row0 = (long)(swz & 31) * 128;
  long col0 = (long)(swz >> 5) * 128;

  const bf16* ga = A  + (row0 + (tid >> 2)) * K + (tid & 3) * 8;
  const bf16* gb = Bt + (col0 + (tid >> 2)) * K + (tid & 3) * 8;

  f32x4 acc[4][4];
  const f32x4 fz = {0.f, 0.f, 0.f, 0.f};
#pragma unroll
  for (int m = 0; m < 4; ++m)
#pragma unroll
    for (int n = 0; n < 4; ++n) acc[m][n] = fz;

  int nk = K >> 5;
  {
    bf16* la = (bf16*)smem + tid * 8;
    bf16* lb = (bf16*)(smem + 8192) + tid * 8;
    gload16(ga, la);  gload16(ga + (long)64 * K, la + 2048);
    gload16(gb, lb);  gload16(gb + (long)64 * K, lb + 2048);
    ga += 32; gb += 32;
  }
  int cur = 0;
  for (int t = 0; t < nk; ++t) {
    __syncthreads();
    if (t + 1 < nk) {
      char* bufb = smem + (cur ^ 1) * 16384;
      bf16* la = (bf16*)bufb + tid * 8;
      bf16* lb = (bf16*)(bufb + 8192) + tid * 8;
      gload16(ga, la);  gload16(ga + (long)64 * K, la + 2048);
      gload16(gb, lb);  gload16(gb + (long)64 * K, lb + 2048);
      ga += 32; gb += 32;
    }
    const bf16* cA = (const bf16*)(smem + cur * 16384);
    const bf16* cB = (const bf16*)(smem + cur * 16384 + 8192);
    bf16x8 af[4], bfr[4];
#pragma unroll
    for (int m = 0; m < 4; ++m)
      af[m] = *(const bf16x8*)(cA + (wr * 64 + m * 16 + lr) * 32 + lg * 8);
#pragma unroll
    for (int n = 0; n < 4; ++n)
      bfr[n] = *(const bf16x8*)(cB + (wc * 64 + n * 16 + lr) * 32 + lg * 8);
#pragma unroll
    for (int m = 0; m < 4; ++m)
#pragma unroll
      for (int n = 0; n < 4; ++n)
        acc[m][n] = __builtin_amdgcn_mfma_f32_16x16x32_bf16(af[m], bfr[n], acc[m][n], 0, 0, 0);
    cur ^= 1;
  }
  __syncthreads();

  bf16* lc = (bf16*)smem;
#pragma unroll
  for (int n = 0; n < 4; ++n) {
    int gcl = wc * 64 + n * 16 + lr;
    float bv = bias ? bias[boff + col0 + gcl] : 0.f;
#pragma unroll
    for (int m = 0; m < 4; ++m) {
      int rb = wr * 64 + m * 16 + lg * 4;
#pragma unroll
      for (int r = 0; r < 4; ++r) {
        float v = acc[m][n][r] + bv;
        if (MODE == 1) v = fmaxf(v, 0.f);
        lc[(rb + r) * 128 + gcl] = (bf16)v;
      }
    }
  }
  __syncthreads();
#pragma unroll
  for (int it = 0; it < 8; ++it) {
    int byte = it * 4096 + tid * 16;
    int rl = byte >> 8;
    int cb = byte & 255;
    *(bf16x8*)((bf16*)outp + (row0 + rl) * N + col0 + (cb >> 1)) =
        *(const bf16x8*)(smem + byte);
  }
}

// ---------------- 128x64 GEMM, bf16 resid += (Wo, FF2) ----------------
__global__ __launch_bounds__(256) void gemm_bt64(const bf16* __restrict__ A,
    const bf16* __restrict__ Bt, const float* __restrict__ bias, long boff,
    bf16* __restrict__ resid, int N, int K) {
  __shared__ __attribute__((aligned(16))) char smem[32768];
  int tid = threadIdx.x;
  int l = tid & 63;
  int w = tid >> 6, wr = w >> 1, wc = w & 1;
  int lg = l >> 4, lr = l & 15;

  int nwg = gridDim.x;
  int fid = blockIdx.x;
  int swz = (fid & 7) * (nwg >> 3) + (fid >> 3);
  long row0 = (long)(swz & 31) * 128;
  long col0 = (long)(swz >> 5) * 64;

  const bf16* ga = A  + (row0 + (tid >> 2)) * K + (tid & 3) * 8;
  const bf16* gb = Bt + (col0 + (tid >> 2)) * K + (tid & 3) * 8;

  f32x4 acc[4][2];
  const f32x4 fz = {0.f, 0.f, 0.f, 0.f};
#pragma unroll
  for (int m = 0; m < 4; ++m)
#pragma unroll
    for (int n = 0; n < 2; ++n) acc[m][n] = fz;

  int nk = K >> 5;
  {
    bf16* la = (bf16*)smem + tid * 8;
    bf16* lb = (bf16*)(smem + 8192) + tid * 8;
    gload16(ga, la);  gload16(ga + (long)64 * K, la + 2048);
    gload16(gb, lb);
    ga += 32; gb += 32;
  }
  int cur = 0;
  for (int t = 0; t < nk; ++t) {
    __syncthreads();
    if (t + 1 < nk) {
      char* bufb = smem + (cur ^ 1) * 12288;
      bf16* la = (bf16*)bufb + tid * 8;
      bf16* lb = (bf16*)(bufb + 8192) + tid * 8;
      gload16(ga, la);  gload16(ga + (long)64 * K, la + 2048);
      gload16(gb, lb);
      ga += 32; gb += 32;
    }
    const bf16* cA = (const bf16*)(smem + cur * 12288);
    const bf16* cB = (const bf16*)(smem + cur * 12288 + 8192);
    bf16x8 af[4], bfr[2];
#pragma unroll
    for (int m = 0; m < 4; ++m)
      af[m] = *(const bf16x8*)(cA + (wr * 64 + m * 16 + lr) * 32 + lg * 8);
#pragma unroll
    for (int n = 0; n < 2; ++n)
      bfr[n] = *(const bf16x8*)(cB + (wc * 32 + n * 16 + lr) * 32 + lg * 8);
#pragma unroll
    for (int m = 0; m < 4; ++m)
#pragma unroll
      for (int n = 0; n < 2; ++n)
        acc[m][n] = __builtin_amdgcn_mfma_f32_16x16x32_bf16(af[m], bfr[n], acc[m][n], 0, 0, 0);
    cur ^= 1;
  }
  __syncthreads();

  // ---- epilogue: [128][64] fp32 C tile in LDS, bf16 RMW stores ----
  float* lcf = (float*)smem;
#pragma unroll
  for (int n = 0; n < 2; ++n) {
    int col = wc * 32 + n * 16 + lr;
    float bv = bias ? bias[boff + col0 + col] : 0.f;
#pragma unroll
    for (int m = 0; m < 4; ++m) {
      int rl = wr * 64 + m * 16 + lg * 4;
#pragma unroll
      for (int r = 0; r < 4; ++r)
        lcf[(rl + r) * 64 + col] = acc[m][n][r] + bv;
    }
  }
  __syncthreads();
#pragma unroll
  for (int it = 0; it < 8; ++it) {
    int byte = it * 4096 + tid * 16;          // 16 B fp32 = 4 values
    int rl = byte >> 8;                       // 256 B per LDS row
    int cb = byte & 255;
    long gr = row0 + rl;
    f32x4 v = *(const f32x4*)(smem + byte);
    bf16* gp = resid + gr * N + col0 + (cb >> 2);
    bf16x4 gold = *(const bf16x4*)gp;
    bf16x4 gnew;
#pragma unroll
    for (int q = 0; q < 4; ++q)
      gnew[q] = (bf16)((float)gold[q] + v[q]);
    *(bf16x4*)gp = gnew;
  }
}

// ---------------- flash attention: KVBLK=32 ----------------
#define TRRD(D, OFF) asm volatile("ds_read_b64_tr_b16 %0, %1 offset:" OFF \
                                  : "=v"(D) : "v"(trp))
__global__ __launch_bounds__(64) void attn_kernel(const bf16* __restrict__ qkv,
                                                  bf16* __restrict__ attout) {
  int fid = blockIdx.x;
  int swzb = (fid & 7) * 384 + (fid >> 3);
  int qt = swzb & 63;
  int bh = swzb >> 6;
  int b = bh / C_H, h = bh % C_H;
  int l = threadIdx.x;
  int lg = l >> 4, lr = l & 15;
  const bf16* base = qkv + (long)b * C_T * QKVN;

  const bf16* qp = base + (long)(qt * 16 + lr) * QKVN + h * C_HS;
  bf16x8 qf0 = *(const bf16x8*)(qp + lg * 8);
  bf16x8 qf1 = *(const bf16x8*)(qp + 32 + lg * 8);

  const f32x4 fz = {0.f, 0.f, 0.f, 0.f};
  f32x4 o[4] = {fz, fz, fz, fz};
  float m_run[4], l_run[4];
#pragma unroll
  for (int r = 0; r < 4; ++r) { m_run[r] = -1e30f; l_run[r] = 0.f; }

  __shared__ __attribute__((aligned(16))) bf16 p_lds[16][40];
  __shared__ __attribute__((aligned(16))) bf16 vt_sub[2048];

  unsigned trp = (unsigned)(unsigned long)
      ((const __attribute__((address_space(3))) char*)vt_sub + l * 8);

  int nkt = (qt * 16 + 15) / 32 + 1;
  for (int kt = 0; kt < nkt; ++kt) {
    int key0 = kt * 32;
    f32x4 sacc[2];
#pragma unroll
    for (int ss = 0; ss < 2; ++ss) {
      const bf16* kp = base + (long)(key0 + ss * 16 + lr) * QKVN + C_D + h * C_HS;
      bf16x8 kf0 = *(const bf16x8*)(kp + lg * 8);
      bf16x8 kf1 = *(const bf16x8*)(kp + 32 + lg * 8);
      f32x4 a = fz;
      a = __builtin_amdgcn_mfma_f32_16x16x32_bf16(qf0, kf0, a, 0, 0, 0);
      a = __builtin_amdgcn_mfma_f32_16x16x32_bf16(qf1, kf1, a, 0, 0, 0);
      sacc[ss] = a;
    }
#pragma unroll
    for (int r = 0; r < 4; ++r) {
      int qrow = qt * 16 + lg * 4 + r;
      bool u0 = (key0 + lr) <= qrow;
      bool u1 = (key0 + 16 + lr) <= qrow;
      float s0 = u0 ? sacc[0][r] * 0.125f : -1e30f;
      float s1 = u1 ? sacc[1][r] * 0.125f : -1e30f;
      float mr = fmaxf(s0, s1);
      mr = fmaxf(mr, __shfl_xor(mr, 1));
      mr = fmaxf(mr, __shfl_xor(mr, 2));
      mr = fmaxf(mr, __shfl_xor(mr, 4));
      mr = fmaxf(mr, __shfl_xor(mr, 8));
      float mnew = fmaxf(m_run[r], mr);
      float scale = __expf(m_run[r] - mnew);
      float p0 = u0 ? __expf(s0 - mnew) : 0.f;
      float p1 = u1 ? __expf(s1 - mnew) : 0.f;
      float rs = p0 + p1;
      rs += __shfl_xor(rs, 1);
      rs += __shfl_xor(rs, 2);
      rs += __shfl_xor(rs, 4);
      rs += __shfl_xor(rs, 8);
      l_run[r] = l_run[r] * scale + rs;
      m_run[r] = mnew;
      o[0][r] *= scale; o[1][r] *= scale; o[2][r] *= scale; o[3][r] *= scale;
      p_lds[lg * 4 + r][lr]      = (bf16)p0;
      p_lds[lg * 4 + r][16 + lr] = (bf16)p1;
    }
#pragma unroll
    for (int it = 0; it < 4; ++it) {
      int kl = it * 8 + (l >> 3);
      int d0 = (l & 7) * 8;
      bf16x8 vv = *(const bf16x8*)(base + (long)(key0 + kl) * QKVN + 2 * C_D + h * C_HS + d0);
      int ba = ((d0 >> 4) << 10) + (((kl >> 2) & 1) << 9) + ((kl >> 3) << 7)
             + ((kl & 3) << 5) + ((d0 & 15) << 1);
      *(bf16x8*)((char*)vt_sub + ba) = vv;
    }
    __syncthreads();
    s16x4 t0a, t0b, t1a, t1b, t2a, t2b, t3a, t3b;
    TRRD(t0a, "0");    TRRD(t0b, "512");
    TRRD(t1a, "1024"); TRRD(t1b, "1536");
    TRRD(t2a, "2048"); TRRD(t2b, "2560");
    TRRD(t3a, "3072"); TRRD(t3b, "3584");
    bf16x8 pf = *(const bf16x8*)(&p_lds[lr][lg * 8]);
    asm volatile("s_waitcnt lgkmcnt(0)" ::: "memory");
    __builtin_amdgcn_sched_barrier(0);
    union uu { short s[8]; bf16x8 v; };
    auto mk = [](s16x4 a, s16x4 bq) {
      uu u;
      u.s[0] = a[0]; u.s[1] = a[1]; u.s[2] = a[2]; u.s[3] = a[3];
      u.s[4] = bq[0]; u.s[5] = bq[1]; u.s[6] = bq[2]; u.s[7] = bq[3];
      return u.v;
    };
    o[0] = __builtin_amdgcn_mfma_f32_16x16x32_bf16(pf, mk(t0a, t0b), o[0], 0, 0, 0);
    o[1] = __builtin_amdgcn_mfma_f32_16x16x32_bf16(pf, mk(t1a, t1b), o[1], 0, 0, 0);
    o[2] = __builtin_amdgcn_mfma_f32_16x16x32_bf16(pf, mk(t2a, t2b), o[2], 0, 0, 0);
    o[3] = __builtin_amdgcn_mfma_f32_16x16x32_bf16(pf, mk(t3a, t3b), o[3], 0, 0, 0);
    __syncthreads();
  }
#pragma unroll
  for (int c = 0; c < 4; ++c)
#pragma unroll
    for (int r = 0; r < 4; ++r) {
      int qrow = qt * 16 + lg * 4 + r;
      attout[((long)b * C_T + qrow) * C_D + h * C_HS + c * 16 + lr] =
          (bf16)(o[c][r] / l_run[r]);
    }
}

// ---------------- loss from partials ----------------
__global__ __launch_bounds__(128) void loss_partial_kernel(const float* __restrict__ lossp,
    const float* __restrict__ logits, const int* __restrict__ targets,
    float* __restrict__ rowloss) {
  int row = blockIdx.x * 128 + threadIdx.x;
  const float* pp = lossp + (long)row * NCB * 2;
  float M = -1e30f, S = 0.f;
  for (int i = 0; i < NCB; ++i) {
    float pm = pp[i * 2], ps = pp[i * 2 + 1];
    float Mn = fmaxf(M, pm);
    S = S * __expf(M - Mn) + ps * __expf(pm - Mn);
    M = Mn;
  }
  float lt = logits[(long)row * C_V + targets[row]];
  rowloss[row] = -(lt - M - logf(S));
}

__global__ __launch_bounds__(256) void loss_final(const float* __restrict__ rowloss,
                                                  float* __restrict__ out) {
  int tid = threadIdx.x;
  float s = 0.f;
  for (int i = tid; i < ROWS; i += 256) s += rowloss[i];
#pragma unroll
  for (int off = 32; off > 0; off >>= 1) s += __shfl_down(s, off);
  __shared__ float sm[4];
  if ((tid & 63) == 0) sm[tid >> 6] = s;
  __syncthreads();
  if (tid == 0) out[0] = (sm[0] + sm[1] + sm[2] + sm[3]) * (1.f / ROWS);
}

// ---------------- launch ----------------
extern "C" void kernel_launch(void* const* d_in, const int* in_sizes, int n_in,
                              void* d_out, int out_size, void* d_ws, size_t ws_size,
                              hipStream_t stream) {
  (void)in_sizes; (void)n_in; (void)out_size; (void)ws_size;
  const int*   idx     = (const int*)  d_in[0];
  const int*   targets = (const int*)  d_in[1];
  const float* tok     = (const float*)d_in[2];
  const float* pos     = (const float*)d_in[3];
  const float* Wq      = (const float*)d_in[4];
  const float* Wk      = (const float*)d_in[5];
  const float* Wv      = (const float*)d_in[6];
  const float* Wo      = (const float*)d_in[7];
  const float* bo      = (const float*)d_in[8];
  const float* W1      = (const float*)d_in[9];
  const float* b1      = (const float*)d_in[10];
  const float* W2      = (const float*)d_in[11];
  const float* b2      = (const float*)d_in[12];
  const float* ln1g    = (const float*)d_in[13];
  const float* ln1b    = (const float*)d_in[14];
  const float* ln2g    = (const float*)d_in[15];
  const float* ln2b    = (const float*)d_in[16];
  const float* lnfg    = (const float*)d_in[17];
  const float* lnfb    = (const float*)d_in[18];
  const float* Wlm     = (const float*)d_in[19];
  const float* blm     = (const float*)d_in[20];

  char* p = (char*)d_ws;
  auto alloc = [&](size_t bytes) {
    char* r = p; p += (bytes + 255) & ~(size_t)255; return r;
  };
  bf16*  x       = (bf16*) alloc((size_t)ROWS * C_D * 2);    // bf16 residual
  bf16*  h       = (bf16*) alloc((size_t)ROWS * C_D * 2);
  bf16*  qkv     = (bf16*) alloc((size_t)ROWS * QKVN * 2);   // \  reused as wlmt
  bf16*  attout  = (bf16*) alloc((size_t)ROWS * C_D * 2);    //  > after layer loop
  bf16*  ffbuf   = (bf16*) alloc((size_t)ROWS * C_FF * 2);   // /
  bf16*  wqkvt   = (bf16*) alloc((size_t)QKVN * C_D * 2);
  bf16*  wot     = (bf16*) alloc((size_t)C_D * C_D * 2);
  bf16*  w1t     = (bf16*) alloc((size_t)C_FF * C_D * 2);
  bf16*  w2t     = (bf16*) alloc((size_t)C_D * C_FF * 2);
  float* rowloss = (float*)alloc((size_t)ROWS * 4);
  float* lossp   = (float*)alloc((size_t)ROWS * NCB * 2 * 4);
  bf16*  wlmt    = qkv;   // alias: 49.15 MB needed, qkv+attout+ffbuf = 50.33 MB

  float* logits = (float*)d_out;

  embed_kernel<<<ROWS * C_D / 256, 256, 0, stream>>>(idx, tok, pos, x);

  for (int l = 0; l < C_L; ++l) {
    transpose_layer_kernel<<<864, 256, 0, stream>>>(
        Wq, Wk, Wv, Wo, W1, W2, wqkvt, wot, w1t, w2t, l);

    ln_kernel<<<ROWS / 8, 512, 0, stream>>>(x, ln1g, ln1b, (long)l * C_D, h);
    gemm_bt<0><<<(QKVN / 128) * 32, 256, 0, stream>>>(
        h, wqkvt, nullptr, 0, qkv, QKVN, C_D);
    attn_kernel<<<C_B * C_H * (C_T / 16), 64, 0, stream>>>(qkv, attout);
    gemm_bt64<<<(C_D / 64) * 32, 256, 0, stream>>>(
        attout, wot, bo, (long)l * C_D, x, C_D, C_D);
    ln_kernel<<<ROWS / 8, 512, 0, stream>>>(x, ln2g, ln2b, (long)l * C_D, h);
    gemm_bt<1><<<(C_FF / 128) * 32, 256, 0, stream>>>(
        h, w1t, b1, (long)l * C_FF, ffbuf, C_FF, C_D);
    gemm_bt64<<<(C_D / 64) * 32, 256, 0, stream>>>(
        ffbuf, w2t, b2, (long)l * C_D, x, C_D, C_FF);
  }

  transpose_kernel<<<(C_V / 32) * (C_D / 32), 256, 0, stream>>>(
      Wlm, wlmt, C_D, C_V, 0, C_V / 32);

  ln_kernel<<<ROWS / 8, 512, 0, stream>>>(x, lnfg, lnfb, 0, h);
  gemm256<<<16 * (C_V / 256), 512, 0, stream>>>(
      h, wlmt, blm, 0, logits, lossp, C_V, C_D);
  loss_partial_kernel<<<ROWS / 128, 128, 0, stream>>>(lossp, logits, targets, rowloss);
  loss_final<<<1, 256, 0, stream>>>(rowloss, logits + (long)ROWS * C_V);
}